// Round 4
// baseline (971.866 us; speedup 1.0000x reference)
//
#include <hip/hip_runtime.h>
#include <math.h>

#define FDIM 64
#define CATDIM 192

// ============ zero bucket counters ============

__global__ void k_zero(int* __restrict__ p, int n) {
    int i = blockIdx.x * blockDim.x + threadIdx.x;
    if (i < n) p[i] = 0;
}

// ============ coarse histogram over dest buckets (dest>>6), 3 graphs ============
// counters: 3*NB ints (~9.4 KB) -> stays hot in L2/atomic path.

__global__ void k_bhist(const int* __restrict__ ei0,
                        const int* __restrict__ ei1,
                        const int* __restrict__ ei2,
                        int* __restrict__ bcnt,    // [3][NB]
                        int NB, int E) {
    int e = blockIdx.x * blockDim.x + threadIdx.x;
    if (e >= E) return;
    atomicAdd(&bcnt[ei0[E + e] >> 6], 1);
    atomicAdd(&bcnt[NB + (ei1[E + e] >> 6)], 1);
    atomicAdd(&bcnt[2 * NB + (ei2[E + e] >> 6)], 1);
}

// ============ per-graph exclusive scan of bucket counts -> bbase, bcur ============

__global__ __launch_bounds__(256) void k_bscan(const int* __restrict__ bcnt,
                                               int* __restrict__ bbase,   // [3][NB+1]
                                               int* __restrict__ bcur,    // [3][NB]
                                               int NB) {
    __shared__ int s[256];
    __shared__ int carry;
    int g = blockIdx.x, tid = threadIdx.x;
    if (tid == 0) carry = 0;
    __syncthreads();
    for (int base = 0; base < NB; base += 256) {
        int i = base + tid;
        int v = (i < NB) ? bcnt[g * NB + i] : 0;
        s[tid] = v;
        __syncthreads();
        for (int d = 1; d < 256; d <<= 1) {
            int t = (tid >= d) ? s[tid - d] : 0;
            __syncthreads();
            s[tid] += t;
            __syncthreads();
        }
        int excl = s[tid] - v + carry;
        if (i < NB) {
            bbase[g * (NB + 1) + i] = excl;
            bcur[g * NB + i] = excl;
        }
        __syncthreads();
        if (tid == 255) carry += s[255];
        __syncthreads();
    }
    if (tid == 0) bbase[g * (NB + 1) + NB] = carry;   // == E
}

// ============ pass A: scatter edges into bucket regions ============
// packed: .x = src | (dest&63)<<16  (N < 65536), .y = weight bits (g>0)

__global__ void k_bfill(const int* __restrict__ ei0,
                        const int* __restrict__ ei1,
                        const int* __restrict__ ei2,
                        const float* __restrict__ w1,
                        const float* __restrict__ w2,
                        int* __restrict__ bcur,      // [3][NB]
                        int2* __restrict__ barr,     // [3][E]
                        int NB, int E) {
    int e = blockIdx.x * blockDim.x + threadIdx.x;
    if (e >= E) return;
    {
        int r = ei0[e], c = ei0[E + e];
        int slot = atomicAdd(&bcur[c >> 6], 1);
        barr[slot] = make_int2(r | ((c & 63) << 16), 0);
    }
    {
        int r = ei1[e], c = ei1[E + e];
        int slot = atomicAdd(&bcur[NB + (c >> 6)], 1);
        barr[E + slot] = make_int2(r | ((c & 63) << 16), __float_as_int(w1[e]));
    }
    {
        int r = ei2[e], c = ei2[E + e];
        int slot = atomicAdd(&bcur[2 * NB + (c >> 6)], 1);
        barr[2 * E + slot] = make_int2(r | ((c & 63) << 16), __float_as_int(w2[e]));
    }
}

// ============ pass B: per-bucket counting sort -> final CSR + rowptr + dis ============
// one block per (bucket, graph). Also computes deg = 1 + sum(w) -> dis = rsqrt.

__global__ __launch_bounds__(256) void k_bsort(const int2* __restrict__ barr,  // [3][E]
                                               const int* __restrict__ bbase,  // [3][NB+1]
                                               int2* __restrict__ csr,         // [3][E] (src, valbits)
                                               int* __restrict__ rowptr,       // [3][N+1]
                                               float* __restrict__ dis,        // [3][N]
                                               int N, int E, int NB) {
    __shared__ int hist[64];
    __shared__ float wsum[64];
    __shared__ int cur[64];
    __shared__ int sc[64];

    const int b = blockIdx.x, g = blockIdx.y, tid = threadIdx.x;
    const int2* bin = barr + (size_t)g * E;
    const int beg = bbase[g * (NB + 1) + b];
    const int end = bbase[g * (NB + 1) + b + 1];

    if (tid < 64) { hist[tid] = 0; wsum[tid] = 1.0f; }   // 1.0 = self-loop weight
    __syncthreads();

    for (int t = beg + tid; t < end; t += 256) {
        int2 p = bin[t];
        int dl = (p.x >> 16) & 63;
        atomicAdd(&hist[dl], 1);
        if (g) atomicAdd(&wsum[dl], __int_as_float(p.y));
    }
    __syncthreads();

    // exclusive scan of hist (full-block Hillis-Steele over 64 entries)
    if (tid < 64) sc[tid] = hist[tid];
    __syncthreads();
    for (int d = 1; d < 64; d <<= 1) {
        int t = 0;
        if (tid < 64 && tid >= d) t = sc[tid - d];
        __syncthreads();
        if (tid < 64) sc[tid] += t;
        __syncthreads();
    }
    if (tid < 64) {
        int excl = sc[tid] - hist[tid];
        cur[tid] = excl;
        int node = b * 64 + tid;
        if (node < N) {
            rowptr[g * (N + 1) + node] = beg + excl;
            float s = g ? wsum[tid] : (1.0f + (float)hist[tid]);
            dis[g * N + node] = rsqrtf(s);
        }
    }
    if (b == NB - 1 && tid == 0) rowptr[g * (N + 1) + N] = end;   // == E
    __syncthreads();

    for (int t = beg + tid; t < end; t += 256) {
        int2 p = bin[t];
        int dl = (p.x >> 16) & 63;
        int pos = atomicAdd(&cur[dl], 1);
        csr[(size_t)g * E + beg + pos] = make_int2(p.x & 0xFFFF, p.y);
    }
}

// ============ premultiply val by dis[src] (streaming 8B RMW) ============

__global__ void k_scale(int2* __restrict__ csr, const float* __restrict__ dis,
                        int N, int E) {
    int idx = blockIdx.x * blockDim.x + threadIdx.x;
    if (idx >= 3 * E) return;
    int g = idx >= 2 * E ? 2 : (idx >= E ? 1 : 0);
    int2 p = csr[idx];
    float d = dis[g * N + p.x];
    float v = (g == 0) ? d : __int_as_float(p.y) * d;
    csr[idx] = make_int2(p.x, __float_as_int(v));
}

// ============ GEMM: out[n][64] = A[n][K] * W[64][K]^T ============

template <int K>
__global__ __launch_bounds__(256) void k_gemm(const float* __restrict__ A,
                                              const float* __restrict__ W,
                                              float* __restrict__ out, int n) {
    __shared__ float wt[K * 65];
    __shared__ float xs[64 * 36];

    const int tid = threadIdx.x;
    const int n0 = blockIdx.x * 64;

    for (int idx = tid; idx < FDIM * K; idx += 256) {
        int fr = idx / K;
        int kr = idx - fr * K;
        wt[kr * 65 + fr] = W[idx];
    }

    const int f = tid & 63;
    const int q = tid >> 6;
    float acc[16];
#pragma unroll
    for (int j = 0; j < 16; ++j) acc[j] = 0.f;

    for (int kc = 0; kc < K; kc += 32) {
        __syncthreads();
#pragma unroll
        for (int u = tid; u < 512; u += 256) {
            int node = u >> 3;
            int k4 = u & 7;
            int gn = n0 + node;
            float4 a = make_float4(0.f, 0.f, 0.f, 0.f);
            if (gn < n) a = *reinterpret_cast<const float4*>(&A[(size_t)gn * K + kc + k4 * 4]);
            *reinterpret_cast<float4*>(&xs[node * 36 + k4 * 4]) = a;
        }
        __syncthreads();

#pragma unroll
        for (int kk = 0; kk < 32; kk += 4) {
            float w0 = wt[(kc + kk + 0) * 65 + f];
            float w1 = wt[(kc + kk + 1) * 65 + f];
            float w2 = wt[(kc + kk + 2) * 65 + f];
            float w3 = wt[(kc + kk + 3) * 65 + f];
#pragma unroll
            for (int jj = 0; jj < 16; ++jj) {
                int j = jj * 4 + q;
                float4 av = *reinterpret_cast<const float4*>(&xs[j * 36 + kk]);
                acc[jj] = fmaf(av.x, w0, fmaf(av.y, w1, fmaf(av.z, w2, fmaf(av.w, w3, acc[jj]))));
            }
        }
    }

#pragma unroll
    for (int jj = 0; jj < 16; ++jj) {
        int node = n0 + jj * 4 + q;
        if (node < n) out[(size_t)node * FDIM + f] = acc[jj];
    }
}

// ============ fused dgconv gather x3 + self-loop + bias + relu ============
// one 64-lane wave per node; lane = feature. 4-way ILP, 8B pair loads.

__global__ __launch_bounds__(256) void k_gather(const float* __restrict__ h,
                                                const float* __restrict__ dis,     // [3][N]
                                                const int* __restrict__ rowptr,    // [3][N+1]
                                                const int2* __restrict__ csr,      // [3][E]
                                                const float* __restrict__ bias,    // [64]
                                                float* __restrict__ cat,           // [N][192]
                                                int N, int E) {
    int i = blockIdx.x * 4 + (threadIdx.x >> 6);
    if (i >= N) return;
    const int lane = threadIdx.x & 63;

    const float hv = h[(size_t)i * FDIM + lane];
    const float b = bias[lane];

#pragma unroll
    for (int g = 0; g < 3; ++g) {
        const int* rp = rowptr + g * (N + 1);
        const int2* cg = csr + (size_t)g * E;
        int beg = rp[i], end = rp[i + 1];
        float dg = dis[g * N + i];

        float acc0 = 0.f, acc1 = 0.f, acc2 = 0.f, acc3 = 0.f;
        for (int base = beg; base < end; base += 64) {
            int idx = base + lane;
            int2 p = (idx < end) ? cg[idx] : make_int2(0, 0);
            int s = p.x;
            float v = __int_as_float(p.y);
            int m = end - base;
            if (m > 64) m = 64;
            int j = 0;
            for (; j + 3 < m; j += 4) {
                int s0 = __shfl(s, j);
                int s1 = __shfl(s, j + 1);
                int s2 = __shfl(s, j + 2);
                int s3 = __shfl(s, j + 3);
                float v0 = __shfl(v, j);
                float v1 = __shfl(v, j + 1);
                float v2 = __shfl(v, j + 2);
                float v3 = __shfl(v, j + 3);
                float a0 = h[(size_t)s0 * FDIM + lane];
                float a1 = h[(size_t)s1 * FDIM + lane];
                float a2 = h[(size_t)s2 * FDIM + lane];
                float a3 = h[(size_t)s3 * FDIM + lane];
                acc0 = fmaf(v0, a0, acc0);
                acc1 = fmaf(v1, a1, acc1);
                acc2 = fmaf(v2, a2, acc2);
                acc3 = fmaf(v3, a3, acc3);
            }
            for (; j < m; ++j) {
                int s0 = __shfl(s, j);
                float v0 = __shfl(v, j);
                acc0 = fmaf(v0, h[(size_t)s0 * FDIM + lane], acc0);
            }
        }
        float outv = dg * ((acc0 + acc1) + (acc2 + acc3)) + dg * dg * hv + b;
        cat[(size_t)i * CATDIM + g * FDIM + lane] = outv > 0.f ? outv : 0.f;
    }
}

// ============ head: pointwise conv (16 out) + log_softmax ============

__global__ __launch_bounds__(256) void k_final(const float* __restrict__ cat,
                                               const float* __restrict__ convw,  // [16][192]
                                               const float* __restrict__ convb,  // [16]
                                               float* __restrict__ out, int n) {
    __shared__ float wl[16 * 196];
    __shared__ float bl[16];
    const int tid = threadIdx.x;
    for (int t = tid; t < 16 * 192; t += 256) {
        int o = t / 192;
        int k = t - o * 192;
        wl[o * 196 + k] = convw[t];
    }
    if (tid < 16) bl[tid] = convb[tid];
    __syncthreads();

    const int o = tid & 15;
    const int node = blockIdx.x * 16 + (tid >> 4);
    const int nc = node < n ? node : n - 1;

    const float4* xr = reinterpret_cast<const float4*>(cat + (size_t)nc * CATDIM);
    const float* wr = &wl[o * 196];
    float acc = bl[o];
#pragma unroll
    for (int k4 = 0; k4 < CATDIM / 4; ++k4) {
        float4 xv = xr[k4];
        acc += xv.x * wr[k4 * 4 + 0] + xv.y * wr[k4 * 4 + 1] +
               xv.z * wr[k4 * 4 + 2] + xv.w * wr[k4 * 4 + 3];
    }

    float m = acc;
    m = fmaxf(m, __shfl_xor(m, 1));
    m = fmaxf(m, __shfl_xor(m, 2));
    m = fmaxf(m, __shfl_xor(m, 4));
    m = fmaxf(m, __shfl_xor(m, 8));
    float s = __expf(acc - m);
    s += __shfl_xor(s, 1);
    s += __shfl_xor(s, 2);
    s += __shfl_xor(s, 4);
    s += __shfl_xor(s, 8);
    if (node < n) out[(size_t)node * 16 + o] = acc - m - logf(s);
}

// ============ launch ============

extern "C" void kernel_launch(void* const* d_in, const int* in_sizes, int n_in,
                              void* d_out, int out_size, void* d_ws, size_t ws_size,
                              hipStream_t stream) {
    const float* x      = (const float*)d_in[0];
    const int*   ei     = (const int*)d_in[1];
    const int*   e_in   = (const int*)d_in[2];
    const int*   e_out  = (const int*)d_in[3];
    const float* in_w   = (const float*)d_in[4];
    const float* out_w  = (const float*)d_in[5];
    const float* lin1_w = (const float*)d_in[6];
    const float* lin2_w = (const float*)d_in[7];
    const float* bias1  = (const float*)d_in[8];
    const float* bias2  = (const float*)d_in[9];
    const float* conv_w = (const float*)d_in[10];
    const float* conv_b = (const float*)d_in[11];
    float* out = (float*)d_out;

    const int N = in_sizes[0] / 128;
    const int E = in_sizes[1] / 2;
    const int NB = (N + 63) >> 6;      // dest buckets of 64 nodes

    // workspace layout (4B units; csr kept 8B-aligned)
    float* ws = (float*)d_ws;
    size_t o = 0;
    float* dis    = ws + o;            o += (size_t)3 * N;
    int*   rowptr = (int*)(ws + o);    o += ((size_t)3 * (N + 1) + 1) & ~1ull;
    int*   bcnt   = (int*)(ws + o);    o += (size_t)3 * NB;
    int*   bbase  = (int*)(ws + o);    o += (size_t)3 * (NB + 1);
    int*   bcur   = (int*)(ws + o);    o += ((size_t)3 * NB + 1) & ~1ull;
    float* h      = ws + o;            o += (size_t)N * FDIM;
    o = (o + 1) & ~1ull;
    int2*  csr    = (int2*)(ws + o);   o += (size_t)6 * E;   // 3E pairs
    o = (o + 1) & ~1ull;
    float* cat    = ws + o;            o += (size_t)N * CATDIM;
    int2*  barr   = (int2*)cat;        // alias: bucket array dead before cat written

    const int B = 256;

    // CSR build (bucketed counting sort) + normalization
    hipLaunchKernelGGL(k_zero, dim3((3 * NB + B - 1) / B), dim3(B), 0, stream, bcnt, 3 * NB);
    hipLaunchKernelGGL(k_bhist, dim3((E + B - 1) / B), dim3(B), 0, stream, ei, e_in, e_out, bcnt, NB, E);
    hipLaunchKernelGGL(k_bscan, dim3(3), dim3(B), 0, stream, bcnt, bbase, bcur, NB);
    hipLaunchKernelGGL(k_bfill, dim3((E + B - 1) / B), dim3(B), 0, stream,
                       ei, e_in, e_out, in_w, out_w, bcur, barr, NB, E);
    hipLaunchKernelGGL(k_bsort, dim3(NB, 3), dim3(B), 0, stream,
                       barr, bbase, csr, rowptr, dis, N, E, NB);
    hipLaunchKernelGGL(k_scale, dim3((3 * E + B - 1) / B), dim3(B), 0, stream, csr, dis, N, E);

    // layer 1
    hipLaunchKernelGGL((k_gemm<128>), dim3((N + 63) / 64), dim3(B), 0, stream, x, lin1_w, h, N);
    hipLaunchKernelGGL(k_gather, dim3((N + 3) / 4), dim3(B), 0, stream,
                       h, dis, rowptr, csr, bias1, cat, N, E);

    // layer 2
    hipLaunchKernelGGL((k_gemm<192>), dim3((N + 63) / 64), dim3(B), 0, stream, cat, lin2_w, h, N);
    hipLaunchKernelGGL(k_gather, dim3((N + 3) / 4), dim3(B), 0, stream,
                       h, dis, rowptr, csr, bias2, cat, N, E);

    // head
    hipLaunchKernelGGL(k_final, dim3((N + 15) / 16), dim3(B), 0, stream, cat, conv_w, conv_b, out, N);
}

// Round 5
// 624.657 us; speedup vs baseline: 1.5558x; 1.5558x over previous
//
#include <hip/hip_runtime.h>
#include <math.h>

#define FDIM 64
#define CATDIM 192
#define CH 8192      // edges per chunk in the binning passes
#define MAXNB 1024   // max dest buckets (N<65536)

// ============ pass H: per-chunk LDS histogram over dest buckets ============
// bh[g][b][c] = #edges of chunk c (graph g) with dest in bucket b. No global atomics.

__global__ __launch_bounds__(256) void k_chist(const int* __restrict__ ei0,
                                               const int* __restrict__ ei1,
                                               const int* __restrict__ ei2,
                                               int* __restrict__ bh,   // [3][NB][nchunks]
                                               int NB, int nchunks, int E) {
    __shared__ int hist[MAXNB];
    const int c = blockIdx.x, g = blockIdx.y, tid = threadIdx.x;
    const int* dest = (g == 0 ? ei0 : g == 1 ? ei1 : ei2) + E;

    for (int i = tid; i < NB; i += 256) hist[i] = 0;
    __syncthreads();

    const int lo = c * CH, hi = min(E, lo + CH);
    for (int i = lo + tid; i < hi; i += 256) atomicAdd(&hist[dest[i] >> 6], 1);
    __syncthreads();

    for (int i = tid; i < NB; i += 256)
        bh[((size_t)g * NB + i) * nchunks + c] = hist[i];
}

// ============ exclusive scan of bh (bucket-major) per graph ============

__global__ __launch_bounds__(256) void k_cscan(int* __restrict__ bh, int L) {
    __shared__ int part[256];
    const int g = blockIdx.x, tid = threadIdx.x;
    int* data = bh + (size_t)g * L;
    const int seg = (L + 255) / 256;
    const int lo = tid * seg, hi = min(L, lo + seg);

    int s = 0;
    for (int j = lo; j < hi; ++j) s += data[j];
    part[tid] = s;
    __syncthreads();
    for (int d = 1; d < 256; d <<= 1) {
        int t = (tid >= d) ? part[tid - d] : 0;
        __syncthreads();
        part[tid] += t;
        __syncthreads();
    }
    int run = part[tid] - s;   // exclusive prefix of this thread's segment
    for (int j = lo; j < hi; ++j) {
        int v = data[j];
        data[j] = run;
        run += v;
    }
}

// ============ bucket bases from scanned bh ============

__global__ void k_bbase(const int* __restrict__ bh, int* __restrict__ bbase,
                        int NB, int nchunks, int E) {
    int i = blockIdx.x * blockDim.x + threadIdx.x;
    if (i >= 3 * NB) return;
    int g = i / NB, b = i - g * NB;
    bbase[g * (NB + 1) + b] = bh[((size_t)g * NB + b) * nchunks];
    if (b == 0) bbase[g * (NB + 1) + NB] = E;
}

// ============ pass F: deterministic binned scatter (LDS cursors only) ============
// packed: .x = src | (dest&63)<<16, .y = weight bits

__global__ __launch_bounds__(256) void k_cfill(const int* __restrict__ ei0,
                                               const int* __restrict__ ei1,
                                               const int* __restrict__ ei2,
                                               const float* __restrict__ w1,
                                               const float* __restrict__ w2,
                                               const int* __restrict__ bh,  // scanned bases
                                               int2* __restrict__ barr,     // [3][E]
                                               int NB, int nchunks, int E) {
    __shared__ int cur[MAXNB];
    const int c = blockIdx.x, g = blockIdx.y, tid = threadIdx.x;
    const int* e = (g == 0 ? ei0 : g == 1 ? ei1 : ei2);
    const float* w = (g == 1 ? w1 : w2);
    const int* srcp = e;
    const int* dest = e + E;
    int2* bout = barr + (size_t)g * E;

    for (int i = tid; i < NB; i += 256)
        cur[i] = bh[((size_t)g * NB + i) * nchunks + c];
    __syncthreads();

    const int lo = c * CH, hi = min(E, lo + CH);
    for (int i = lo + tid; i < hi; i += 256) {
        int d = dest[i];
        int slot = atomicAdd(&cur[d >> 6], 1);
        float wv = (g == 0) ? 0.f : w[i];
        bout[slot] = make_int2(srcp[i] | ((d & 63) << 16), __float_as_int(wv));
    }
}

// ============ per-bucket counting sort -> final CSR + rowptr + dis ============

__global__ __launch_bounds__(256) void k_bsort(const int2* __restrict__ barr,  // [3][E]
                                               const int* __restrict__ bbase,  // [3][NB+1]
                                               int2* __restrict__ csr,         // [3][E]
                                               int* __restrict__ rowptr,       // [3][N+1]
                                               float* __restrict__ dis,        // [3][N]
                                               int N, int E, int NB) {
    __shared__ int hist[64];
    __shared__ float wsum[64];
    __shared__ int cur[64];
    __shared__ int sc[64];

    const int b = blockIdx.x, g = blockIdx.y, tid = threadIdx.x;
    const int2* bin = barr + (size_t)g * E;
    const int beg = bbase[g * (NB + 1) + b];
    const int end = bbase[g * (NB + 1) + b + 1];

    if (tid < 64) { hist[tid] = 0; wsum[tid] = 1.0f; }   // 1.0 = self-loop weight
    __syncthreads();

    for (int t = beg + tid; t < end; t += 256) {
        int2 p = bin[t];
        int dl = (p.x >> 16) & 63;
        atomicAdd(&hist[dl], 1);
        if (g) atomicAdd(&wsum[dl], __int_as_float(p.y));
    }
    __syncthreads();

    if (tid < 64) sc[tid] = hist[tid];
    __syncthreads();
    for (int d = 1; d < 64; d <<= 1) {
        int t = 0;
        if (tid < 64 && tid >= d) t = sc[tid - d];
        __syncthreads();
        if (tid < 64) sc[tid] += t;
        __syncthreads();
    }
    if (tid < 64) {
        int excl = sc[tid] - hist[tid];
        cur[tid] = excl;
        int node = b * 64 + tid;
        if (node < N) {
            rowptr[g * (N + 1) + node] = beg + excl;
            float s = g ? wsum[tid] : (1.0f + (float)hist[tid]);
            dis[g * N + node] = rsqrtf(s);
        }
    }
    if (b == NB - 1 && tid == 0) rowptr[g * (N + 1) + N] = end;
    __syncthreads();

    for (int t = beg + tid; t < end; t += 256) {
        int2 p = bin[t];
        int dl = (p.x >> 16) & 63;
        int pos = atomicAdd(&cur[dl], 1);
        csr[(size_t)g * E + beg + pos] = make_int2(p.x & 0xFFFF, p.y);
    }
}

// ============ premultiply val by dis[src] ============

__global__ void k_scale(int2* __restrict__ csr, const float* __restrict__ dis,
                        int N, int E) {
    int idx = blockIdx.x * blockDim.x + threadIdx.x;
    if (idx >= 3 * E) return;
    int g = idx >= 2 * E ? 2 : (idx >= E ? 1 : 0);
    int2 p = csr[idx];
    float d = dis[g * N + p.x];
    float v = (g == 0) ? d : __int_as_float(p.y) * d;
    csr[idx] = make_int2(p.x, __float_as_int(v));
}

// ============ GEMM: out[n][64] = A[n][K] * W[64][K]^T ============

template <int K>
__global__ __launch_bounds__(256) void k_gemm(const float* __restrict__ A,
                                              const float* __restrict__ W,
                                              float* __restrict__ out, int n) {
    __shared__ float wt[K * 65];
    __shared__ float xs[64 * 36];

    const int tid = threadIdx.x;
    const int n0 = blockIdx.x * 64;

    for (int idx = tid; idx < FDIM * K; idx += 256) {
        int fr = idx / K;
        int kr = idx - fr * K;
        wt[kr * 65 + fr] = W[idx];
    }

    const int f = tid & 63;
    const int q = tid >> 6;
    float acc[16];
#pragma unroll
    for (int j = 0; j < 16; ++j) acc[j] = 0.f;

    for (int kc = 0; kc < K; kc += 32) {
        __syncthreads();
#pragma unroll
        for (int u = tid; u < 512; u += 256) {
            int node = u >> 3;
            int k4 = u & 7;
            int gn = n0 + node;
            float4 a = make_float4(0.f, 0.f, 0.f, 0.f);
            if (gn < n) a = *reinterpret_cast<const float4*>(&A[(size_t)gn * K + kc + k4 * 4]);
            *reinterpret_cast<float4*>(&xs[node * 36 + k4 * 4]) = a;
        }
        __syncthreads();

#pragma unroll
        for (int kk = 0; kk < 32; kk += 4) {
            float w0 = wt[(kc + kk + 0) * 65 + f];
            float w1 = wt[(kc + kk + 1) * 65 + f];
            float w2 = wt[(kc + kk + 2) * 65 + f];
            float w3 = wt[(kc + kk + 3) * 65 + f];
#pragma unroll
            for (int jj = 0; jj < 16; ++jj) {
                int j = jj * 4 + q;
                float4 av = *reinterpret_cast<const float4*>(&xs[j * 36 + kk]);
                acc[jj] = fmaf(av.x, w0, fmaf(av.y, w1, fmaf(av.z, w2, fmaf(av.w, w3, acc[jj]))));
            }
        }
    }

#pragma unroll
    for (int jj = 0; jj < 16; ++jj) {
        int node = n0 + jj * 4 + q;
        if (node < n) out[(size_t)node * FDIM + f] = acc[jj];
    }
}

// ============ fused dgconv gather x3 + self-loop + bias + relu ============

__global__ __launch_bounds__(256) void k_gather(const float* __restrict__ h,
                                                const float* __restrict__ dis,     // [3][N]
                                                const int* __restrict__ rowptr,    // [3][N+1]
                                                const int2* __restrict__ csr,      // [3][E]
                                                const float* __restrict__ bias,    // [64]
                                                float* __restrict__ cat,           // [N][192]
                                                int N, int E) {
    int i = blockIdx.x * 4 + (threadIdx.x >> 6);
    if (i >= N) return;
    const int lane = threadIdx.x & 63;

    const float hv = h[(size_t)i * FDIM + lane];
    const float b = bias[lane];

#pragma unroll
    for (int g = 0; g < 3; ++g) {
        const int* rp = rowptr + g * (N + 1);
        const int2* cg = csr + (size_t)g * E;
        int beg = rp[i], end = rp[i + 1];
        float dg = dis[g * N + i];

        float acc0 = 0.f, acc1 = 0.f, acc2 = 0.f, acc3 = 0.f;
        for (int base = beg; base < end; base += 64) {
            int idx = base + lane;
            int2 p = (idx < end) ? cg[idx] : make_int2(0, 0);
            int s = p.x;
            float v = __int_as_float(p.y);
            int m = end - base;
            if (m > 64) m = 64;
            int j = 0;
            for (; j + 3 < m; j += 4) {
                int s0 = __shfl(s, j);
                int s1 = __shfl(s, j + 1);
                int s2 = __shfl(s, j + 2);
                int s3 = __shfl(s, j + 3);
                float v0 = __shfl(v, j);
                float v1 = __shfl(v, j + 1);
                float v2 = __shfl(v, j + 2);
                float v3 = __shfl(v, j + 3);
                float a0 = h[(size_t)s0 * FDIM + lane];
                float a1 = h[(size_t)s1 * FDIM + lane];
                float a2 = h[(size_t)s2 * FDIM + lane];
                float a3 = h[(size_t)s3 * FDIM + lane];
                acc0 = fmaf(v0, a0, acc0);
                acc1 = fmaf(v1, a1, acc1);
                acc2 = fmaf(v2, a2, acc2);
                acc3 = fmaf(v3, a3, acc3);
            }
            for (; j < m; ++j) {
                int s0 = __shfl(s, j);
                float v0 = __shfl(v, j);
                acc0 = fmaf(v0, h[(size_t)s0 * FDIM + lane], acc0);
            }
        }
        float outv = dg * ((acc0 + acc1) + (acc2 + acc3)) + dg * dg * hv + b;
        cat[(size_t)i * CATDIM + g * FDIM + lane] = outv > 0.f ? outv : 0.f;
    }
}

// ============ head: pointwise conv (16 out) + log_softmax ============

__global__ __launch_bounds__(256) void k_final(const float* __restrict__ cat,
                                               const float* __restrict__ convw,  // [16][192]
                                               const float* __restrict__ convb,  // [16]
                                               float* __restrict__ out, int n) {
    __shared__ float wl[16 * 196];
    __shared__ float bl[16];
    const int tid = threadIdx.x;
    for (int t = tid; t < 16 * 192; t += 256) {
        int o = t / 192;
        int k = t - o * 192;
        wl[o * 196 + k] = convw[t];
    }
    if (tid < 16) bl[tid] = convb[tid];
    __syncthreads();

    const int o = tid & 15;
    const int node = blockIdx.x * 16 + (tid >> 4);
    const int nc = node < n ? node : n - 1;

    const float4* xr = reinterpret_cast<const float4*>(cat + (size_t)nc * CATDIM);
    const float* wr = &wl[o * 196];
    float acc = bl[o];
#pragma unroll
    for (int k4 = 0; k4 < CATDIM / 4; ++k4) {
        float4 xv = xr[k4];
        acc += xv.x * wr[k4 * 4 + 0] + xv.y * wr[k4 * 4 + 1] +
               xv.z * wr[k4 * 4 + 2] + xv.w * wr[k4 * 4 + 3];
    }

    float m = acc;
    m = fmaxf(m, __shfl_xor(m, 1));
    m = fmaxf(m, __shfl_xor(m, 2));
    m = fmaxf(m, __shfl_xor(m, 4));
    m = fmaxf(m, __shfl_xor(m, 8));
    float s = __expf(acc - m);
    s += __shfl_xor(s, 1);
    s += __shfl_xor(s, 2);
    s += __shfl_xor(s, 4);
    s += __shfl_xor(s, 8);
    if (node < n) out[(size_t)node * 16 + o] = acc - m - logf(s);
}

// ============ launch ============

extern "C" void kernel_launch(void* const* d_in, const int* in_sizes, int n_in,
                              void* d_out, int out_size, void* d_ws, size_t ws_size,
                              hipStream_t stream) {
    const float* x      = (const float*)d_in[0];
    const int*   ei     = (const int*)d_in[1];
    const int*   e_in   = (const int*)d_in[2];
    const int*   e_out  = (const int*)d_in[3];
    const float* in_w   = (const float*)d_in[4];
    const float* out_w  = (const float*)d_in[5];
    const float* lin1_w = (const float*)d_in[6];
    const float* lin2_w = (const float*)d_in[7];
    const float* bias1  = (const float*)d_in[8];
    const float* bias2  = (const float*)d_in[9];
    const float* conv_w = (const float*)d_in[10];
    const float* conv_b = (const float*)d_in[11];
    float* out = (float*)d_out;

    const int N = in_sizes[0] / 128;
    const int E = in_sizes[1] / 2;
    const int NB = (N + 63) >> 6;              // dest buckets of 64 nodes
    const int nchunks = (E + CH - 1) / CH;
    const int L = NB * nchunks;

    // workspace layout (4B units; int2 arrays 8B-aligned)
    float* ws = (float*)d_ws;
    size_t o = 0;
    float* dis    = ws + o;            o += (size_t)3 * N;
    int*   rowptr = (int*)(ws + o);    o += ((size_t)3 * (N + 1) + 1) & ~1ull;
    int*   bbase  = (int*)(ws + o);    o += ((size_t)3 * (NB + 1) + 1) & ~1ull;
    int*   bh     = (int*)(ws + o);    o += ((size_t)3 * L + 1) & ~1ull;
    float* h      = ws + o;            o += (size_t)N * FDIM;
    o = (o + 1) & ~1ull;
    int2*  csr    = (int2*)(ws + o);   o += (size_t)6 * E;
    o = (o + 1) & ~1ull;
    float* cat    = ws + o;            o += (size_t)N * CATDIM;
    int2*  barr   = (int2*)cat;        // alias: bucket array dead before cat written

    const int B = 256;

    // CSR build: deterministic two-pass binning (no global atomics)
    hipLaunchKernelGGL(k_chist, dim3(nchunks, 3), dim3(B), 0, stream, ei, e_in, e_out, bh, NB, nchunks, E);
    hipLaunchKernelGGL(k_cscan, dim3(3), dim3(B), 0, stream, bh, L);
    hipLaunchKernelGGL(k_bbase, dim3((3 * NB + B - 1) / B), dim3(B), 0, stream, bh, bbase, NB, nchunks, E);
    hipLaunchKernelGGL(k_cfill, dim3(nchunks, 3), dim3(B), 0, stream,
                       ei, e_in, e_out, in_w, out_w, bh, barr, NB, nchunks, E);
    hipLaunchKernelGGL(k_bsort, dim3(NB, 3), dim3(B), 0, stream,
                       barr, bbase, csr, rowptr, dis, N, E, NB);
    hipLaunchKernelGGL(k_scale, dim3((3 * E + B - 1) / B), dim3(B), 0, stream, csr, dis, N, E);

    // layer 1
    hipLaunchKernelGGL((k_gemm<128>), dim3((N + 63) / 64), dim3(B), 0, stream, x, lin1_w, h, N);
    hipLaunchKernelGGL(k_gather, dim3((N + 3) / 4), dim3(B), 0, stream,
                       h, dis, rowptr, csr, bias1, cat, N, E);

    // layer 2
    hipLaunchKernelGGL((k_gemm<192>), dim3((N + 63) / 64), dim3(B), 0, stream, cat, lin2_w, h, N);
    hipLaunchKernelGGL(k_gather, dim3((N + 3) / 4), dim3(B), 0, stream,
                       h, dis, rowptr, csr, bias2, cat, N, E);

    // head
    hipLaunchKernelGGL(k_final, dim3((N + 15) / 16), dim3(B), 0, stream, cat, conv_w, conv_b, out, N);
}

// Round 6
// 520.993 us; speedup vs baseline: 1.8654x; 1.1990x over previous
//
#include <hip/hip_runtime.h>
#include <math.h>

#define FDIM 64
#define CATDIM 192
#define CH 8192      // edges per chunk in the binning passes
#define MAXNB 1024   // max dest buckets (N<65536)
#define SCTILE 1024  // elements per block in the bh scan

// ============ pass H: per-chunk LDS histogram over dest buckets ============
// bh[g][b][c] = #edges of chunk c (graph g) with dest in bucket b. No global atomics.

__global__ __launch_bounds__(256) void k_chist(const int* __restrict__ ei0,
                                               const int* __restrict__ ei1,
                                               const int* __restrict__ ei2,
                                               int* __restrict__ bh,   // [3][NB][nchunks]
                                               int NB, int nchunks, int E) {
    __shared__ int hist[MAXNB];
    const int c = blockIdx.x, g = blockIdx.y, tid = threadIdx.x;
    const int* dest = (g == 0 ? ei0 : g == 1 ? ei1 : ei2) + E;

    for (int i = tid; i < NB; i += 256) hist[i] = 0;
    __syncthreads();

    const int lo = c * CH, hi = min(E, lo + CH);
    for (int i = lo + tid; i < hi; i += 256) atomicAdd(&hist[dest[i] >> 6], 1);
    __syncthreads();

    for (int i = tid; i < NB; i += 256)
        bh[((size_t)g * NB + i) * nchunks + c] = hist[i];
}

// ============ 3-phase parallel exclusive scan of bh per graph ============

__global__ __launch_bounds__(256) void k_scan_a(const int* __restrict__ bh,
                                                int* __restrict__ bsum,   // [3][nblkS]
                                                int L, int nblkS) {
    __shared__ int s[256];
    const int b = blockIdx.x, g = blockIdx.y, tid = threadIdx.x;
    const int* data = bh + (size_t)g * L;
    const int base = b * SCTILE + tid * 4;
    int v = 0;
#pragma unroll
    for (int j = 0; j < 4; ++j) {
        int idx = base + j;
        if (idx < L) v += data[idx];
    }
    s[tid] = v;
    __syncthreads();
    for (int d = 128; d > 0; d >>= 1) {
        if (tid < d) s[tid] += s[tid + d];
        __syncthreads();
    }
    if (tid == 0) bsum[g * nblkS + b] = s[0];
}

__global__ __launch_bounds__(256) void k_scan_b(int* __restrict__ bsum, int nblkS) {
    __shared__ int s[256];
    const int g = blockIdx.x, tid = threadIdx.x;
    int v = (tid < nblkS) ? bsum[g * nblkS + tid] : 0;
    s[tid] = v;
    __syncthreads();
    for (int d = 1; d < 256; d <<= 1) {
        int t = (tid >= d) ? s[tid - d] : 0;
        __syncthreads();
        s[tid] += t;
        __syncthreads();
    }
    if (tid < nblkS) bsum[g * nblkS + tid] = s[tid] - v;   // exclusive
}

__global__ __launch_bounds__(256) void k_scan_c(int* __restrict__ bh,
                                                const int* __restrict__ bsum,
                                                int L, int nblkS) {
    __shared__ int s[256];
    const int b = blockIdx.x, g = blockIdx.y, tid = threadIdx.x;
    int* data = bh + (size_t)g * L;
    const int base = b * SCTILE + tid * 4;

    int e0 = 0, e1 = 0, e2 = 0, e3 = 0;
    if (base + 0 < L) e0 = data[base + 0];
    if (base + 1 < L) e1 = data[base + 1];
    if (base + 2 < L) e2 = data[base + 2];
    if (base + 3 < L) e3 = data[base + 3];
    int tot = e0 + e1 + e2 + e3;
    s[tid] = tot;
    __syncthreads();
    for (int d = 1; d < 256; d <<= 1) {
        int t = (tid >= d) ? s[tid - d] : 0;
        __syncthreads();
        s[tid] += t;
        __syncthreads();
    }
    int run = bsum[g * nblkS + b] + s[tid] - tot;
    if (base + 0 < L) { data[base + 0] = run; run += e0; }
    if (base + 1 < L) { data[base + 1] = run; run += e1; }
    if (base + 2 < L) { data[base + 2] = run; run += e2; }
    if (base + 3 < L) { data[base + 3] = run; run += e3; }
}

// ============ bucket bases from scanned bh ============

__global__ void k_bbase(const int* __restrict__ bh, int* __restrict__ bbase,
                        int NB, int nchunks, int E) {
    int i = blockIdx.x * blockDim.x + threadIdx.x;
    if (i >= 3 * NB) return;
    int g = i / NB, b = i - g * NB;
    bbase[g * (NB + 1) + b] = bh[((size_t)g * NB + b) * nchunks];
    if (b == 0) bbase[g * (NB + 1) + NB] = E;
}

// ============ pass F: deterministic binned scatter (LDS cursors only) ============
// packed: .x = src | (dest&63)<<16, .y = weight bits

__global__ __launch_bounds__(256) void k_cfill(const int* __restrict__ ei0,
                                               const int* __restrict__ ei1,
                                               const int* __restrict__ ei2,
                                               const float* __restrict__ w1,
                                               const float* __restrict__ w2,
                                               const int* __restrict__ bh,  // scanned bases
                                               int2* __restrict__ barr,     // [3][E]
                                               int NB, int nchunks, int E) {
    __shared__ int cur[MAXNB];
    const int c = blockIdx.x, g = blockIdx.y, tid = threadIdx.x;
    const int* e = (g == 0 ? ei0 : g == 1 ? ei1 : ei2);
    const float* w = (g == 1 ? w1 : w2);
    const int* srcp = e;
    const int* dest = e + E;
    int2* bout = barr + (size_t)g * E;

    for (int i = tid; i < NB; i += 256)
        cur[i] = bh[((size_t)g * NB + i) * nchunks + c];
    __syncthreads();

    const int lo = c * CH, hi = min(E, lo + CH);
    for (int i = lo + tid; i < hi; i += 256) {
        int d = dest[i];
        int slot = atomicAdd(&cur[d >> 6], 1);
        float wv = (g == 0) ? 0.f : w[i];
        bout[slot] = make_int2(srcp[i] | ((d & 63) << 16), __float_as_int(wv));
    }
}

// ============ per-bucket counting sort -> final CSR + rowptr + dis ============

__global__ __launch_bounds__(256) void k_bsort(const int2* __restrict__ barr,  // [3][E]
                                               const int* __restrict__ bbase,  // [3][NB+1]
                                               int2* __restrict__ csr,         // [3][E]
                                               int* __restrict__ rowptr,       // [3][N+1]
                                               float* __restrict__ dis,        // [3][N]
                                               int N, int E, int NB) {
    __shared__ int hist[64];
    __shared__ float wsum[64];
    __shared__ int cur[64];
    __shared__ int sc[64];

    const int b = blockIdx.x, g = blockIdx.y, tid = threadIdx.x;
    const int2* bin = barr + (size_t)g * E;
    const int beg = bbase[g * (NB + 1) + b];
    const int end = bbase[g * (NB + 1) + b + 1];

    if (tid < 64) { hist[tid] = 0; wsum[tid] = 1.0f; }   // 1.0 = self-loop weight
    __syncthreads();

    for (int t = beg + tid; t < end; t += 256) {
        int2 p = bin[t];
        int dl = (p.x >> 16) & 63;
        atomicAdd(&hist[dl], 1);
        if (g) atomicAdd(&wsum[dl], __int_as_float(p.y));
    }
    __syncthreads();

    if (tid < 64) sc[tid] = hist[tid];
    __syncthreads();
    for (int d = 1; d < 64; d <<= 1) {
        int t = 0;
        if (tid < 64 && tid >= d) t = sc[tid - d];
        __syncthreads();
        if (tid < 64) sc[tid] += t;
        __syncthreads();
    }
    if (tid < 64) {
        int excl = sc[tid] - hist[tid];
        cur[tid] = excl;
        int node = b * 64 + tid;
        if (node < N) {
            rowptr[g * (N + 1) + node] = beg + excl;
            float s = g ? wsum[tid] : (1.0f + (float)hist[tid]);
            dis[g * N + node] = rsqrtf(s);
        }
    }
    if (b == NB - 1 && tid == 0) rowptr[g * (N + 1) + N] = end;
    __syncthreads();

    for (int t = beg + tid; t < end; t += 256) {
        int2 p = bin[t];
        int dl = (p.x >> 16) & 63;
        int pos = atomicAdd(&cur[dl], 1);
        csr[(size_t)g * E + beg + pos] = make_int2(p.x & 0xFFFF, p.y);
    }
}

// ============ premultiply val by dis[src] ============

__global__ void k_scale(int2* __restrict__ csr, const float* __restrict__ dis,
                        int N, int E) {
    int idx = blockIdx.x * blockDim.x + threadIdx.x;
    if (idx >= 3 * E) return;
    int g = idx >= 2 * E ? 2 : (idx >= E ? 1 : 0);
    int2 p = csr[idx];
    float d = dis[g * N + p.x];
    float v = (g == 0) ? d : __int_as_float(p.y) * d;
    csr[idx] = make_int2(p.x, __float_as_int(v));
}

// ============ GEMM: out[n][64] = A[n][K] * W[64][K]^T ============

template <int K>
__global__ __launch_bounds__(256) void k_gemm(const float* __restrict__ A,
                                              const float* __restrict__ W,
                                              float* __restrict__ out, int n) {
    __shared__ float wt[K * 65];
    __shared__ float xs[64 * 36];

    const int tid = threadIdx.x;
    const int n0 = blockIdx.x * 64;

    for (int idx = tid; idx < FDIM * K; idx += 256) {
        int fr = idx / K;
        int kr = idx - fr * K;
        wt[kr * 65 + fr] = W[idx];
    }

    const int f = tid & 63;
    const int q = tid >> 6;
    float acc[16];
#pragma unroll
    for (int j = 0; j < 16; ++j) acc[j] = 0.f;

    for (int kc = 0; kc < K; kc += 32) {
        __syncthreads();
#pragma unroll
        for (int u = tid; u < 512; u += 256) {
            int node = u >> 3;
            int k4 = u & 7;
            int gn = n0 + node;
            float4 a = make_float4(0.f, 0.f, 0.f, 0.f);
            if (gn < n) a = *reinterpret_cast<const float4*>(&A[(size_t)gn * K + kc + k4 * 4]);
            *reinterpret_cast<float4*>(&xs[node * 36 + k4 * 4]) = a;
        }
        __syncthreads();

#pragma unroll
        for (int kk = 0; kk < 32; kk += 4) {
            float w0 = wt[(kc + kk + 0) * 65 + f];
            float w1 = wt[(kc + kk + 1) * 65 + f];
            float w2 = wt[(kc + kk + 2) * 65 + f];
            float w3 = wt[(kc + kk + 3) * 65 + f];
#pragma unroll
            for (int jj = 0; jj < 16; ++jj) {
                int j = jj * 4 + q;
                float4 av = *reinterpret_cast<const float4*>(&xs[j * 36 + kk]);
                acc[jj] = fmaf(av.x, w0, fmaf(av.y, w1, fmaf(av.z, w2, fmaf(av.w, w3, acc[jj]))));
            }
        }
    }

#pragma unroll
    for (int jj = 0; jj < 16; ++jj) {
        int node = n0 + jj * 4 + q;
        if (node < n) out[(size_t)node * FDIM + f] = acc[jj];
    }
}

// ============ fused dgconv gather x3 + self-loop + bias + relu ============

__global__ __launch_bounds__(256) void k_gather(const float* __restrict__ h,
                                                const float* __restrict__ dis,     // [3][N]
                                                const int* __restrict__ rowptr,    // [3][N+1]
                                                const int2* __restrict__ csr,      // [3][E]
                                                const float* __restrict__ bias,    // [64]
                                                float* __restrict__ cat,           // [N][192]
                                                int N, int E) {
    int i = blockIdx.x * 4 + (threadIdx.x >> 6);
    if (i >= N) return;
    const int lane = threadIdx.x & 63;

    const float hv = h[(size_t)i * FDIM + lane];
    const float b = bias[lane];

#pragma unroll
    for (int g = 0; g < 3; ++g) {
        const int* rp = rowptr + g * (N + 1);
        const int2* cg = csr + (size_t)g * E;
        int beg = rp[i], end = rp[i + 1];
        float dg = dis[g * N + i];

        float acc0 = 0.f, acc1 = 0.f, acc2 = 0.f, acc3 = 0.f;
        for (int base = beg; base < end; base += 64) {
            int idx = base + lane;
            int2 p = (idx < end) ? cg[idx] : make_int2(0, 0);
            int s = p.x;
            float v = __int_as_float(p.y);
            int m = end - base;
            if (m > 64) m = 64;
            int j = 0;
            for (; j + 3 < m; j += 4) {
                int s0 = __shfl(s, j);
                int s1 = __shfl(s, j + 1);
                int s2 = __shfl(s, j + 2);
                int s3 = __shfl(s, j + 3);
                float v0 = __shfl(v, j);
                float v1 = __shfl(v, j + 1);
                float v2 = __shfl(v, j + 2);
                float v3 = __shfl(v, j + 3);
                float a0 = h[(size_t)s0 * FDIM + lane];
                float a1 = h[(size_t)s1 * FDIM + lane];
                float a2 = h[(size_t)s2 * FDIM + lane];
                float a3 = h[(size_t)s3 * FDIM + lane];
                acc0 = fmaf(v0, a0, acc0);
                acc1 = fmaf(v1, a1, acc1);
                acc2 = fmaf(v2, a2, acc2);
                acc3 = fmaf(v3, a3, acc3);
            }
            for (; j < m; ++j) {
                int s0 = __shfl(s, j);
                float v0 = __shfl(v, j);
                acc0 = fmaf(v0, h[(size_t)s0 * FDIM + lane], acc0);
            }
        }
        float outv = dg * ((acc0 + acc1) + (acc2 + acc3)) + dg * dg * hv + b;
        cat[(size_t)i * CATDIM + g * FDIM + lane] = outv > 0.f ? outv : 0.f;
    }
}

// ============ head: pointwise conv (16 out) + log_softmax ============

__global__ __launch_bounds__(256) void k_final(const float* __restrict__ cat,
                                               const float* __restrict__ convw,  // [16][192]
                                               const float* __restrict__ convb,  // [16]
                                               float* __restrict__ out, int n) {
    __shared__ float wl[16 * 196];
    __shared__ float bl[16];
    const int tid = threadIdx.x;
    for (int t = tid; t < 16 * 192; t += 256) {
        int o = t / 192;
        int k = t - o * 192;
        wl[o * 196 + k] = convw[t];
    }
    if (tid < 16) bl[tid] = convb[tid];
    __syncthreads();

    const int o = tid & 15;
    const int node = blockIdx.x * 16 + (tid >> 4);
    const int nc = node < n ? node : n - 1;

    const float4* xr = reinterpret_cast<const float4*>(cat + (size_t)nc * CATDIM);
    const float* wr = &wl[o * 196];
    float acc = bl[o];
#pragma unroll
    for (int k4 = 0; k4 < CATDIM / 4; ++k4) {
        float4 xv = xr[k4];
        acc += xv.x * wr[k4 * 4 + 0] + xv.y * wr[k4 * 4 + 1] +
               xv.z * wr[k4 * 4 + 2] + xv.w * wr[k4 * 4 + 3];
    }

    float m = acc;
    m = fmaxf(m, __shfl_xor(m, 1));
    m = fmaxf(m, __shfl_xor(m, 2));
    m = fmaxf(m, __shfl_xor(m, 4));
    m = fmaxf(m, __shfl_xor(m, 8));
    float s = __expf(acc - m);
    s += __shfl_xor(s, 1);
    s += __shfl_xor(s, 2);
    s += __shfl_xor(s, 4);
    s += __shfl_xor(s, 8);
    if (node < n) out[(size_t)node * 16 + o] = acc - m - logf(s);
}

// ============ launch ============

extern "C" void kernel_launch(void* const* d_in, const int* in_sizes, int n_in,
                              void* d_out, int out_size, void* d_ws, size_t ws_size,
                              hipStream_t stream) {
    const float* x      = (const float*)d_in[0];
    const int*   ei     = (const int*)d_in[1];
    const int*   e_in   = (const int*)d_in[2];
    const int*   e_out  = (const int*)d_in[3];
    const float* in_w   = (const float*)d_in[4];
    const float* out_w  = (const float*)d_in[5];
    const float* lin1_w = (const float*)d_in[6];
    const float* lin2_w = (const float*)d_in[7];
    const float* bias1  = (const float*)d_in[8];
    const float* bias2  = (const float*)d_in[9];
    const float* conv_w = (const float*)d_in[10];
    const float* conv_b = (const float*)d_in[11];
    float* out = (float*)d_out;

    const int N = in_sizes[0] / 128;
    const int E = in_sizes[1] / 2;
    const int NB = (N + 63) >> 6;              // dest buckets of 64 nodes
    const int nchunks = (E + CH - 1) / CH;
    const int L = NB * nchunks;
    const int nblkS = (L + SCTILE - 1) / SCTILE;   // scan blocks per graph (<=256)

    // workspace layout (4B units; int2 arrays 8B-aligned)
    float* ws = (float*)d_ws;
    size_t o = 0;
    float* dis    = ws + o;            o += (size_t)3 * N;
    int*   rowptr = (int*)(ws + o);    o += ((size_t)3 * (N + 1) + 1) & ~1ull;
    int*   bbase  = (int*)(ws + o);    o += ((size_t)3 * (NB + 1) + 1) & ~1ull;
    int*   bsum   = (int*)(ws + o);    o += ((size_t)3 * nblkS + 1) & ~1ull;
    int*   bh     = (int*)(ws + o);    o += ((size_t)3 * L + 1) & ~1ull;
    float* h      = ws + o;            o += (size_t)N * FDIM;
    o = (o + 1) & ~1ull;
    int2*  csr    = (int2*)(ws + o);   o += (size_t)6 * E;
    o = (o + 1) & ~1ull;
    float* cat    = ws + o;            o += (size_t)N * CATDIM;
    int2*  barr   = (int2*)cat;        // alias: bucket array dead before cat written

    const int B = 256;

    // CSR build: deterministic two-pass binning (no global atomics)
    hipLaunchKernelGGL(k_chist, dim3(nchunks, 3), dim3(B), 0, stream, ei, e_in, e_out, bh, NB, nchunks, E);
    hipLaunchKernelGGL(k_scan_a, dim3(nblkS, 3), dim3(B), 0, stream, bh, bsum, L, nblkS);
    hipLaunchKernelGGL(k_scan_b, dim3(3), dim3(B), 0, stream, bsum, nblkS);
    hipLaunchKernelGGL(k_scan_c, dim3(nblkS, 3), dim3(B), 0, stream, bh, bsum, L, nblkS);
    hipLaunchKernelGGL(k_bbase, dim3((3 * NB + B - 1) / B), dim3(B), 0, stream, bh, bbase, NB, nchunks, E);
    hipLaunchKernelGGL(k_cfill, dim3(nchunks, 3), dim3(B), 0, stream,
                       ei, e_in, e_out, in_w, out_w, bh, barr, NB, nchunks, E);
    hipLaunchKernelGGL(k_bsort, dim3(NB, 3), dim3(B), 0, stream,
                       barr, bbase, csr, rowptr, dis, N, E, NB);
    hipLaunchKernelGGL(k_scale, dim3((3 * E + B - 1) / B), dim3(B), 0, stream, csr, dis, N, E);

    // layer 1
    hipLaunchKernelGGL((k_gemm<128>), dim3((N + 63) / 64), dim3(B), 0, stream, x, lin1_w, h, N);
    hipLaunchKernelGGL(k_gather, dim3((N + 3) / 4), dim3(B), 0, stream,
                       h, dis, rowptr, csr, bias1, cat, N, E);

    // layer 2
    hipLaunchKernelGGL((k_gemm<192>), dim3((N + 63) / 64), dim3(B), 0, stream, cat, lin2_w, h, N);
    hipLaunchKernelGGL(k_gather, dim3((N + 3) / 4), dim3(B), 0, stream,
                       h, dis, rowptr, csr, bias2, cat, N, E);

    // head
    hipLaunchKernelGGL(k_final, dim3((N + 15) / 16), dim3(B), 0, stream, cat, conv_w, conv_b, out, N);
}

// Round 7
// 426.312 us; speedup vs baseline: 2.2797x; 1.2221x over previous
//
#include <hip/hip_runtime.h>
#include <hip/hip_fp16.h>
#include <math.h>

#define FDIM 64
#define CATDIM 192
#define CH 8192      // edges per chunk in the binning passes
#define MAXNB 1024   // max dest buckets (N<65536)
#define SCTILE 1024  // elements per block in the bh scan

// ============ pass H: per-chunk LDS histogram over dest buckets ============

__global__ __launch_bounds__(256) void k_chist(const int* __restrict__ ei0,
                                               const int* __restrict__ ei1,
                                               const int* __restrict__ ei2,
                                               int* __restrict__ bh,   // [3][NB][nchunks]
                                               int NB, int nchunks, int E) {
    __shared__ int hist[MAXNB];
    const int c = blockIdx.x, g = blockIdx.y, tid = threadIdx.x;
    const int* dest = (g == 0 ? ei0 : g == 1 ? ei1 : ei2) + E;

    for (int i = tid; i < NB; i += 256) hist[i] = 0;
    __syncthreads();

    const int lo = c * CH, hi = min(E, lo + CH);
    for (int i = lo + tid; i < hi; i += 256) atomicAdd(&hist[dest[i] >> 6], 1);
    __syncthreads();

    for (int i = tid; i < NB; i += 256)
        bh[((size_t)g * NB + i) * nchunks + c] = hist[i];
}

// ============ 3-phase parallel exclusive scan of bh per graph ============

__global__ __launch_bounds__(256) void k_scan_a(const int* __restrict__ bh,
                                                int* __restrict__ bsum,   // [3][nblkS]
                                                int L, int nblkS) {
    __shared__ int s[256];
    const int b = blockIdx.x, g = blockIdx.y, tid = threadIdx.x;
    const int* data = bh + (size_t)g * L;
    const int base = b * SCTILE + tid * 4;
    int v = 0;
#pragma unroll
    for (int j = 0; j < 4; ++j) {
        int idx = base + j;
        if (idx < L) v += data[idx];
    }
    s[tid] = v;
    __syncthreads();
    for (int d = 128; d > 0; d >>= 1) {
        if (tid < d) s[tid] += s[tid + d];
        __syncthreads();
    }
    if (tid == 0) bsum[g * nblkS + b] = s[0];
}

__global__ __launch_bounds__(256) void k_scan_b(int* __restrict__ bsum, int nblkS) {
    __shared__ int s[256];
    const int g = blockIdx.x, tid = threadIdx.x;
    int v = (tid < nblkS) ? bsum[g * nblkS + tid] : 0;
    s[tid] = v;
    __syncthreads();
    for (int d = 1; d < 256; d <<= 1) {
        int t = (tid >= d) ? s[tid - d] : 0;
        __syncthreads();
        s[tid] += t;
        __syncthreads();
    }
    if (tid < nblkS) bsum[g * nblkS + tid] = s[tid] - v;   // exclusive
}

__global__ __launch_bounds__(256) void k_scan_c(int* __restrict__ bh,
                                                const int* __restrict__ bsum,
                                                int L, int nblkS) {
    __shared__ int s[256];
    const int b = blockIdx.x, g = blockIdx.y, tid = threadIdx.x;
    int* data = bh + (size_t)g * L;
    const int base = b * SCTILE + tid * 4;

    int e0 = 0, e1 = 0, e2 = 0, e3 = 0;
    if (base + 0 < L) e0 = data[base + 0];
    if (base + 1 < L) e1 = data[base + 1];
    if (base + 2 < L) e2 = data[base + 2];
    if (base + 3 < L) e3 = data[base + 3];
    int tot = e0 + e1 + e2 + e3;
    s[tid] = tot;
    __syncthreads();
    for (int d = 1; d < 256; d <<= 1) {
        int t = (tid >= d) ? s[tid - d] : 0;
        __syncthreads();
        s[tid] += t;
        __syncthreads();
    }
    int run = bsum[g * nblkS + b] + s[tid] - tot;
    if (base + 0 < L) { data[base + 0] = run; run += e0; }
    if (base + 1 < L) { data[base + 1] = run; run += e1; }
    if (base + 2 < L) { data[base + 2] = run; run += e2; }
    if (base + 3 < L) { data[base + 3] = run; run += e3; }
}

// ============ bucket bases from scanned bh ============

__global__ void k_bbase(const int* __restrict__ bh, int* __restrict__ bbase,
                        int NB, int nchunks, int E) {
    int i = blockIdx.x * blockDim.x + threadIdx.x;
    if (i >= 3 * NB) return;
    int g = i / NB, b = i - g * NB;
    bbase[g * (NB + 1) + b] = bh[((size_t)g * NB + b) * nchunks];
    if (b == 0) bbase[g * (NB + 1) + NB] = E;
}

// ============ pass F: deterministic binned scatter (LDS cursors only) ============

__global__ __launch_bounds__(256) void k_cfill(const int* __restrict__ ei0,
                                               const int* __restrict__ ei1,
                                               const int* __restrict__ ei2,
                                               const float* __restrict__ w1,
                                               const float* __restrict__ w2,
                                               const int* __restrict__ bh,  // scanned bases
                                               int2* __restrict__ barr,     // [3][E]
                                               int NB, int nchunks, int E) {
    __shared__ int cur[MAXNB];
    const int c = blockIdx.x, g = blockIdx.y, tid = threadIdx.x;
    const int* e = (g == 0 ? ei0 : g == 1 ? ei1 : ei2);
    const float* w = (g == 1 ? w1 : w2);
    const int* srcp = e;
    const int* dest = e + E;
    int2* bout = barr + (size_t)g * E;

    for (int i = tid; i < NB; i += 256)
        cur[i] = bh[((size_t)g * NB + i) * nchunks + c];
    __syncthreads();

    const int lo = c * CH, hi = min(E, lo + CH);
    for (int i = lo + tid; i < hi; i += 256) {
        int d = dest[i];
        int slot = atomicAdd(&cur[d >> 6], 1);
        float wv = (g == 0) ? 0.f : w[i];
        bout[slot] = make_int2(srcp[i] | ((d & 63) << 16), __float_as_int(wv));
    }
}

// ============ per-bucket counting sort -> final CSR (4B packed) + rowptr + dis ============
// csr entry: src:16 | fp16(w):16  (w rescaled to dis[src]*w by k_scale)

__global__ __launch_bounds__(256) void k_bsort(const int2* __restrict__ barr,  // [3][E]
                                               const int* __restrict__ bbase,  // [3][NB+1]
                                               unsigned* __restrict__ csr,     // [3][E]
                                               int* __restrict__ rowptr,       // [3][N+1]
                                               float* __restrict__ dis,        // [3][N]
                                               int N, int E, int NB) {
    __shared__ int hist[64];
    __shared__ float wsum[64];
    __shared__ int cur[64];
    __shared__ int sc[64];

    const int b = blockIdx.x, g = blockIdx.y, tid = threadIdx.x;
    const int2* bin = barr + (size_t)g * E;
    const int beg = bbase[g * (NB + 1) + b];
    const int end = bbase[g * (NB + 1) + b + 1];

    if (tid < 64) { hist[tid] = 0; wsum[tid] = 1.0f; }   // 1.0 = self-loop weight
    __syncthreads();

    for (int t = beg + tid; t < end; t += 256) {
        int2 p = bin[t];
        int dl = (p.x >> 16) & 63;
        atomicAdd(&hist[dl], 1);
        if (g) atomicAdd(&wsum[dl], __int_as_float(p.y));
    }
    __syncthreads();

    if (tid < 64) sc[tid] = hist[tid];
    __syncthreads();
    for (int d = 1; d < 64; d <<= 1) {
        int t = 0;
        if (tid < 64 && tid >= d) t = sc[tid - d];
        __syncthreads();
        if (tid < 64) sc[tid] += t;
        __syncthreads();
    }
    if (tid < 64) {
        int excl = sc[tid] - hist[tid];
        cur[tid] = excl;
        int node = b * 64 + tid;
        if (node < N) {
            rowptr[g * (N + 1) + node] = beg + excl;
            float s = g ? wsum[tid] : (1.0f + (float)hist[tid]);
            dis[g * N + node] = rsqrtf(s);
        }
    }
    if (b == NB - 1 && tid == 0) rowptr[g * (N + 1) + N] = end;
    __syncthreads();

    for (int t = beg + tid; t < end; t += 256) {
        int2 p = bin[t];
        int dl = (p.x >> 16) & 63;
        int pos = atomicAdd(&cur[dl], 1);
        unsigned short wb = __half_as_ushort(__float2half(__int_as_float(p.y)));
        csr[(size_t)g * E + beg + pos] = (unsigned)(p.x & 0xFFFF) | ((unsigned)wb << 16);
    }
}

// ============ premultiply val by dis[src] (fp32 math, fp16 store) ============

__global__ void k_scale(unsigned* __restrict__ csr, const float* __restrict__ dis,
                        int N, int E) {
    int idx = blockIdx.x * blockDim.x + threadIdx.x;
    if (idx >= 3 * E) return;
    int g = idx >= 2 * E ? 2 : (idx >= E ? 1 : 0);
    unsigned u = csr[idx];
    int s = u & 0xFFFFu;
    float d = dis[g * N + s];
    float v = (g == 0) ? d
                       : __half2float(__ushort_as_half((unsigned short)(u >> 16))) * d;
    csr[idx] = (u & 0xFFFFu) |
               ((unsigned)__half_as_ushort(__float2half(v)) << 16);
}

// ============ GEMM: out[n][64] = A[n][K] * W[64][K]^T, fp16 output ============

template <typename T> __device__ inline float4 load4f(const T* p);
template <> __device__ inline float4 load4f<float>(const float* p) {
    return *reinterpret_cast<const float4*>(p);
}
template <> __device__ inline float4 load4f<__half>(const __half* p) {
    __half2 a = *reinterpret_cast<const __half2*>(p);
    __half2 b = *reinterpret_cast<const __half2*>(p + 2);
    float2 fa = __half22float2(a), fb = __half22float2(b);
    return make_float4(fa.x, fa.y, fb.x, fb.y);
}

template <int K, typename TA>
__global__ __launch_bounds__(256) void k_gemm(const TA* __restrict__ A,
                                              const float* __restrict__ W,
                                              __half* __restrict__ out, int n) {
    __shared__ float wt[K * 65];
    __shared__ float xs[64 * 36];

    const int tid = threadIdx.x;
    const int n0 = blockIdx.x * 64;

    for (int idx = tid; idx < FDIM * K; idx += 256) {
        int fr = idx / K;
        int kr = idx - fr * K;
        wt[kr * 65 + fr] = W[idx];
    }

    const int f = tid & 63;
    const int q = tid >> 6;
    float acc[16];
#pragma unroll
    for (int j = 0; j < 16; ++j) acc[j] = 0.f;

    for (int kc = 0; kc < K; kc += 32) {
        __syncthreads();
#pragma unroll
        for (int u = tid; u < 512; u += 256) {
            int node = u >> 3;
            int k4 = u & 7;
            int gn = n0 + node;
            float4 a = make_float4(0.f, 0.f, 0.f, 0.f);
            if (gn < n) a = load4f(&A[(size_t)gn * K + kc + k4 * 4]);
            *reinterpret_cast<float4*>(&xs[node * 36 + k4 * 4]) = a;
        }
        __syncthreads();

#pragma unroll
        for (int kk = 0; kk < 32; kk += 4) {
            float w0 = wt[(kc + kk + 0) * 65 + f];
            float w1 = wt[(kc + kk + 1) * 65 + f];
            float w2 = wt[(kc + kk + 2) * 65 + f];
            float w3 = wt[(kc + kk + 3) * 65 + f];
#pragma unroll
            for (int jj = 0; jj < 16; ++jj) {
                int j = jj * 4 + q;
                float4 av = *reinterpret_cast<const float4*>(&xs[j * 36 + kk]);
                acc[jj] = fmaf(av.x, w0, fmaf(av.y, w1, fmaf(av.z, w2, fmaf(av.w, w3, acc[jj]))));
            }
        }
    }

#pragma unroll
    for (int jj = 0; jj < 16; ++jj) {
        int node = n0 + jj * 4 + q;
        if (node < n) out[(size_t)node * FDIM + f] = __float2half(acc[jj]);
    }
}

// ============ fused dgconv gather x3 + self-loop + bias + relu (fp16 h/cat) ============

__global__ __launch_bounds__(256) void k_gather(const __half* __restrict__ h,
                                                const float* __restrict__ dis,     // [3][N]
                                                const int* __restrict__ rowptr,    // [3][N+1]
                                                const unsigned* __restrict__ csr,  // [3][E]
                                                const float* __restrict__ bias,    // [64]
                                                __half* __restrict__ cat,          // [N][192]
                                                int N, int E) {
    int i = blockIdx.x * 4 + (threadIdx.x >> 6);
    if (i >= N) return;
    const int lane = threadIdx.x & 63;

    const float hv = __half2float(h[(size_t)i * FDIM + lane]);
    const float b = bias[lane];

#pragma unroll
    for (int g = 0; g < 3; ++g) {
        const int* rp = rowptr + g * (N + 1);
        const unsigned* cg = csr + (size_t)g * E;
        int beg = rp[i], end = rp[i + 1];
        float dg = dis[g * N + i];

        float acc0 = 0.f, acc1 = 0.f, acc2 = 0.f, acc3 = 0.f;
        for (int base = beg; base < end; base += 64) {
            int idx = base + lane;
            unsigned u = (idx < end) ? cg[idx] : 0u;
            int s = (int)(u & 0xFFFFu);
            float v = __half2float(__ushort_as_half((unsigned short)(u >> 16)));
            int m = end - base;
            if (m > 64) m = 64;
            int j = 0;
            for (; j + 3 < m; j += 4) {
                int s0 = __shfl(s, j);
                int s1 = __shfl(s, j + 1);
                int s2 = __shfl(s, j + 2);
                int s3 = __shfl(s, j + 3);
                float v0 = __shfl(v, j);
                float v1 = __shfl(v, j + 1);
                float v2 = __shfl(v, j + 2);
                float v3 = __shfl(v, j + 3);
                float a0 = __half2float(h[(size_t)s0 * FDIM + lane]);
                float a1 = __half2float(h[(size_t)s1 * FDIM + lane]);
                float a2 = __half2float(h[(size_t)s2 * FDIM + lane]);
                float a3 = __half2float(h[(size_t)s3 * FDIM + lane]);
                acc0 = fmaf(v0, a0, acc0);
                acc1 = fmaf(v1, a1, acc1);
                acc2 = fmaf(v2, a2, acc2);
                acc3 = fmaf(v3, a3, acc3);
            }
            for (; j < m; ++j) {
                int s0 = __shfl(s, j);
                float v0 = __shfl(v, j);
                acc0 = fmaf(v0, __half2float(h[(size_t)s0 * FDIM + lane]), acc0);
            }
        }
        float outv = dg * ((acc0 + acc1) + (acc2 + acc3)) + dg * dg * hv + b;
        cat[(size_t)i * CATDIM + g * FDIM + lane] = __float2half(outv > 0.f ? outv : 0.f);
    }
}

// ============ head: pointwise conv (16 out) + log_softmax (fp16 cat) ============

__global__ __launch_bounds__(256) void k_final(const __half* __restrict__ cat,
                                               const float* __restrict__ convw,  // [16][192]
                                               const float* __restrict__ convb,  // [16]
                                               float* __restrict__ out, int n) {
    __shared__ float wl[16 * 196];
    __shared__ float bl[16];
    const int tid = threadIdx.x;
    for (int t = tid; t < 16 * 192; t += 256) {
        int o = t / 192;
        int k = t - o * 192;
        wl[o * 196 + k] = convw[t];
    }
    if (tid < 16) bl[tid] = convb[tid];
    __syncthreads();

    const int o = tid & 15;
    const int node = blockIdx.x * 16 + (tid >> 4);
    const int nc = node < n ? node : n - 1;

    const float4* xr4 = reinterpret_cast<const float4*>(cat + (size_t)nc * CATDIM);
    const float* wr = &wl[o * 196];
    float acc = bl[o];
#pragma unroll
    for (int k8 = 0; k8 < CATDIM / 8; ++k8) {
        float4 raw = xr4[k8];
        const __half2* hp = reinterpret_cast<const __half2*>(&raw);
        float2 f0 = __half22float2(hp[0]);
        float2 f1 = __half22float2(hp[1]);
        float2 f2 = __half22float2(hp[2]);
        float2 f3 = __half22float2(hp[3]);
        const float* w8 = wr + k8 * 8;
        acc += f0.x * w8[0] + f0.y * w8[1] + f1.x * w8[2] + f1.y * w8[3] +
               f2.x * w8[4] + f2.y * w8[5] + f3.x * w8[6] + f3.y * w8[7];
    }

    float m = acc;
    m = fmaxf(m, __shfl_xor(m, 1));
    m = fmaxf(m, __shfl_xor(m, 2));
    m = fmaxf(m, __shfl_xor(m, 4));
    m = fmaxf(m, __shfl_xor(m, 8));
    float s = __expf(acc - m);
    s += __shfl_xor(s, 1);
    s += __shfl_xor(s, 2);
    s += __shfl_xor(s, 4);
    s += __shfl_xor(s, 8);
    if (node < n) out[(size_t)node * 16 + o] = acc - m - logf(s);
}

// ============ launch ============

extern "C" void kernel_launch(void* const* d_in, const int* in_sizes, int n_in,
                              void* d_out, int out_size, void* d_ws, size_t ws_size,
                              hipStream_t stream) {
    const float* x      = (const float*)d_in[0];
    const int*   ei     = (const int*)d_in[1];
    const int*   e_in   = (const int*)d_in[2];
    const int*   e_out  = (const int*)d_in[3];
    const float* in_w   = (const float*)d_in[4];
    const float* out_w  = (const float*)d_in[5];
    const float* lin1_w = (const float*)d_in[6];
    const float* lin2_w = (const float*)d_in[7];
    const float* bias1  = (const float*)d_in[8];
    const float* bias2  = (const float*)d_in[9];
    const float* conv_w = (const float*)d_in[10];
    const float* conv_b = (const float*)d_in[11];
    float* out = (float*)d_out;

    const int N = in_sizes[0] / 128;
    const int E = in_sizes[1] / 2;
    const int NB = (N + 63) >> 6;              // dest buckets of 64 nodes
    const int nchunks = (E + CH - 1) / CH;
    const int L = NB * nchunks;
    const int nblkS = (L + SCTILE - 1) / SCTILE;   // scan blocks per graph (<=256)

    // workspace layout (4B units; wider types kept 8B/16B aligned)
    float* ws = (float*)d_ws;
    size_t o = 0;
    float* dis    = ws + o;            o += (size_t)3 * N;
    int*   rowptr = (int*)(ws + o);    o += ((size_t)3 * (N + 1) + 1) & ~1ull;
    int*   bbase  = (int*)(ws + o);    o += ((size_t)3 * (NB + 1) + 1) & ~1ull;
    int*   bsum   = (int*)(ws + o);    o += ((size_t)3 * nblkS + 1) & ~1ull;
    int*   bh     = (int*)(ws + o);    o += ((size_t)3 * L + 3) & ~3ull;
    __half* h     = (__half*)(ws + o); o += (size_t)N * (FDIM / 2);       // fp16
    o = (o + 3) & ~3ull;
    unsigned* csr = (unsigned*)(ws + o); o += (size_t)3 * E;              // 4B packed
    o = (o + 3) & ~3ull;
    __half* cat   = (__half*)(ws + o); o += (size_t)N * (CATDIM / 2);     // fp16
    int2*  barr   = (int2*)cat;        // alias: bucket array dead before cat written

    const int B = 256;

    // CSR build: deterministic two-pass binning (no global atomics)
    hipLaunchKernelGGL(k_chist, dim3(nchunks, 3), dim3(B), 0, stream, ei, e_in, e_out, bh, NB, nchunks, E);
    hipLaunchKernelGGL(k_scan_a, dim3(nblkS, 3), dim3(B), 0, stream, bh, bsum, L, nblkS);
    hipLaunchKernelGGL(k_scan_b, dim3(3), dim3(B), 0, stream, bsum, nblkS);
    hipLaunchKernelGGL(k_scan_c, dim3(nblkS, 3), dim3(B), 0, stream, bh, bsum, L, nblkS);
    hipLaunchKernelGGL(k_bbase, dim3((3 * NB + B - 1) / B), dim3(B), 0, stream, bh, bbase, NB, nchunks, E);
    hipLaunchKernelGGL(k_cfill, dim3(nchunks, 3), dim3(B), 0, stream,
                       ei, e_in, e_out, in_w, out_w, bh, barr, NB, nchunks, E);
    hipLaunchKernelGGL(k_bsort, dim3(NB, 3), dim3(B), 0, stream,
                       barr, bbase, csr, rowptr, dis, N, E, NB);
    hipLaunchKernelGGL(k_scale, dim3((3 * E + B - 1) / B), dim3(B), 0, stream, csr, dis, N, E);

    // layer 1
    hipLaunchKernelGGL((k_gemm<128, float>), dim3((N + 63) / 64), dim3(B), 0, stream, x, lin1_w, h, N);
    hipLaunchKernelGGL(k_gather, dim3((N + 3) / 4), dim3(B), 0, stream,
                       h, dis, rowptr, csr, bias1, cat, N, E);

    // layer 2
    hipLaunchKernelGGL((k_gemm<192, __half>), dim3((N + 63) / 64), dim3(B), 0, stream, cat, lin2_w, h, N);
    hipLaunchKernelGGL(k_gather, dim3((N + 3) / 4), dim3(B), 0, stream,
                       h, dis, rowptr, csr, bias2, cat, N, E);

    // head
    hipLaunchKernelGGL(k_final, dim3((N + 15) / 16), dim3(B), 0, stream, cat, conv_w, conv_b, out, N);
}

// Round 8
// 421.291 us; speedup vs baseline: 2.3069x; 1.0119x over previous
//
#include <hip/hip_runtime.h>
#include <hip/hip_fp16.h>
#include <math.h>

#define FDIM 64
#define CATDIM 192
#define CH 8192      // edges per chunk in the binning passes
#define MAXNB 1024   // max dest buckets (N<65536)
#define SCTILE 1024  // elements per block in the bh scan

// ============ pass H: per-chunk LDS histogram over dest buckets ============

__global__ __launch_bounds__(256) void k_chist(const int* __restrict__ ei0,
                                               const int* __restrict__ ei1,
                                               const int* __restrict__ ei2,
                                               int* __restrict__ bh,   // [3][NB][nchunks]
                                               int NB, int nchunks, int E) {
    __shared__ int hist[MAXNB];
    const int c = blockIdx.x, g = blockIdx.y, tid = threadIdx.x;
    const int* dest = (g == 0 ? ei0 : g == 1 ? ei1 : ei2) + E;

    for (int i = tid; i < NB; i += 256) hist[i] = 0;
    __syncthreads();

    const int lo = c * CH, hi = min(E, lo + CH);
    for (int i = lo + tid; i < hi; i += 256) atomicAdd(&hist[dest[i] >> 6], 1);
    __syncthreads();

    for (int i = tid; i < NB; i += 256)
        bh[((size_t)g * NB + i) * nchunks + c] = hist[i];
}

// ============ 3-phase parallel exclusive scan of bh per graph ============

__global__ __launch_bounds__(256) void k_scan_a(const int* __restrict__ bh,
                                                int* __restrict__ bsum,   // [3][nblkS]
                                                int L, int nblkS) {
    __shared__ int s[256];
    const int b = blockIdx.x, g = blockIdx.y, tid = threadIdx.x;
    const int* data = bh + (size_t)g * L;
    const int base = b * SCTILE + tid * 4;
    int v = 0;
#pragma unroll
    for (int j = 0; j < 4; ++j) {
        int idx = base + j;
        if (idx < L) v += data[idx];
    }
    s[tid] = v;
    __syncthreads();
    for (int d = 128; d > 0; d >>= 1) {
        if (tid < d) s[tid] += s[tid + d];
        __syncthreads();
    }
    if (tid == 0) bsum[g * nblkS + b] = s[0];
}

__global__ __launch_bounds__(256) void k_scan_b(int* __restrict__ bsum, int nblkS) {
    __shared__ int s[256];
    const int g = blockIdx.x, tid = threadIdx.x;
    int v = (tid < nblkS) ? bsum[g * nblkS + tid] : 0;
    s[tid] = v;
    __syncthreads();
    for (int d = 1; d < 256; d <<= 1) {
        int t = (tid >= d) ? s[tid - d] : 0;
        __syncthreads();
        s[tid] += t;
        __syncthreads();
    }
    if (tid < nblkS) bsum[g * nblkS + tid] = s[tid] - v;   // exclusive
}

__global__ __launch_bounds__(256) void k_scan_c(int* __restrict__ bh,
                                                const int* __restrict__ bsum,
                                                int L, int nblkS) {
    __shared__ int s[256];
    const int b = blockIdx.x, g = blockIdx.y, tid = threadIdx.x;
    int* data = bh + (size_t)g * L;
    const int base = b * SCTILE + tid * 4;

    int e0 = 0, e1 = 0, e2 = 0, e3 = 0;
    if (base + 0 < L) e0 = data[base + 0];
    if (base + 1 < L) e1 = data[base + 1];
    if (base + 2 < L) e2 = data[base + 2];
    if (base + 3 < L) e3 = data[base + 3];
    int tot = e0 + e1 + e2 + e3;
    s[tid] = tot;
    __syncthreads();
    for (int d = 1; d < 256; d <<= 1) {
        int t = (tid >= d) ? s[tid - d] : 0;
        __syncthreads();
        s[tid] += t;
        __syncthreads();
    }
    int run = bsum[g * nblkS + b] + s[tid] - tot;
    if (base + 0 < L) { data[base + 0] = run; run += e0; }
    if (base + 1 < L) { data[base + 1] = run; run += e1; }
    if (base + 2 < L) { data[base + 2] = run; run += e2; }
    if (base + 3 < L) { data[base + 3] = run; run += e3; }
}

// ============ bucket bases from scanned bh ============

__global__ void k_bbase(const int* __restrict__ bh, int* __restrict__ bbase,
                        int NB, int nchunks, int E) {
    int i = blockIdx.x * blockDim.x + threadIdx.x;
    if (i >= 3 * NB) return;
    int g = i / NB, b = i - g * NB;
    bbase[g * (NB + 1) + b] = bh[((size_t)g * NB + b) * nchunks];
    if (b == 0) bbase[g * (NB + 1) + NB] = E;
}

// ============ pass F: deterministic binned scatter (LDS cursors only) ============

__global__ __launch_bounds__(256) void k_cfill(const int* __restrict__ ei0,
                                               const int* __restrict__ ei1,
                                               const int* __restrict__ ei2,
                                               const float* __restrict__ w1,
                                               const float* __restrict__ w2,
                                               const int* __restrict__ bh,  // scanned bases
                                               int2* __restrict__ barr,     // [3][E]
                                               int NB, int nchunks, int E) {
    __shared__ int cur[MAXNB];
    const int c = blockIdx.x, g = blockIdx.y, tid = threadIdx.x;
    const int* e = (g == 0 ? ei0 : g == 1 ? ei1 : ei2);
    const float* w = (g == 1 ? w1 : w2);
    const int* srcp = e;
    const int* dest = e + E;
    int2* bout = barr + (size_t)g * E;

    for (int i = tid; i < NB; i += 256)
        cur[i] = bh[((size_t)g * NB + i) * nchunks + c];
    __syncthreads();

    const int lo = c * CH, hi = min(E, lo + CH);
    for (int i = lo + tid; i < hi; i += 256) {
        int d = dest[i];
        int slot = atomicAdd(&cur[d >> 6], 1);
        float wv = (g == 0) ? 0.f : w[i];
        bout[slot] = make_int2(srcp[i] | ((d & 63) << 16), __float_as_int(wv));
    }
}

// ============ per-bucket counting sort -> final CSR (4B packed) + rowptr + dis ============
// csr entry: src:16 | fp16(w):16  (w rescaled to dis[src]*w by k_scale)

__global__ __launch_bounds__(256) void k_bsort(const int2* __restrict__ barr,  // [3][E]
                                               const int* __restrict__ bbase,  // [3][NB+1]
                                               unsigned* __restrict__ csr,     // [3][E]
                                               int* __restrict__ rowptr,       // [3][N+1]
                                               float* __restrict__ dis,        // [3][N]
                                               int N, int E, int NB) {
    __shared__ int hist[64];
    __shared__ float wsum[64];
    __shared__ int cur[64];
    __shared__ int sc[64];

    const int b = blockIdx.x, g = blockIdx.y, tid = threadIdx.x;
    const int2* bin = barr + (size_t)g * E;
    const int beg = bbase[g * (NB + 1) + b];
    const int end = bbase[g * (NB + 1) + b + 1];

    if (tid < 64) { hist[tid] = 0; wsum[tid] = 1.0f; }   // 1.0 = self-loop weight
    __syncthreads();

    for (int t = beg + tid; t < end; t += 256) {
        int2 p = bin[t];
        int dl = (p.x >> 16) & 63;
        atomicAdd(&hist[dl], 1);
        if (g) atomicAdd(&wsum[dl], __int_as_float(p.y));
    }
    __syncthreads();

    if (tid < 64) sc[tid] = hist[tid];
    __syncthreads();
    for (int d = 1; d < 64; d <<= 1) {
        int t = 0;
        if (tid < 64 && tid >= d) t = sc[tid - d];
        __syncthreads();
        if (tid < 64) sc[tid] += t;
        __syncthreads();
    }
    if (tid < 64) {
        int excl = sc[tid] - hist[tid];
        cur[tid] = excl;
        int node = b * 64 + tid;
        if (node < N) {
            rowptr[g * (N + 1) + node] = beg + excl;
            float s = g ? wsum[tid] : (1.0f + (float)hist[tid]);
            dis[g * N + node] = rsqrtf(s);
        }
    }
    if (b == NB - 1 && tid == 0) rowptr[g * (N + 1) + N] = end;
    __syncthreads();

    for (int t = beg + tid; t < end; t += 256) {
        int2 p = bin[t];
        int dl = (p.x >> 16) & 63;
        int pos = atomicAdd(&cur[dl], 1);
        unsigned short wb = __half_as_ushort(__float2half(__int_as_float(p.y)));
        csr[(size_t)g * E + beg + pos] = (unsigned)(p.x & 0xFFFF) | ((unsigned)wb << 16);
    }
}

// ============ premultiply val by dis[src] (fp32 math, fp16 store) ============

__global__ void k_scale(unsigned* __restrict__ csr, const float* __restrict__ dis,
                        int N, int E) {
    int idx = blockIdx.x * blockDim.x + threadIdx.x;
    if (idx >= 3 * E) return;
    int g = idx >= 2 * E ? 2 : (idx >= E ? 1 : 0);
    unsigned u = csr[idx];
    int s = u & 0xFFFFu;
    float d = dis[g * N + s];
    float v = (g == 0) ? d
                       : __half2float(__ushort_as_half((unsigned short)(u >> 16))) * d;
    csr[idx] = (u & 0xFFFFu) |
               ((unsigned)__half_as_ushort(__float2half(v)) << 16);
}

// ============ GEMM: out[n][64] = A[n][K] * W[64][K]^T, fp16 output ============

template <typename T> __device__ inline float4 load4f(const T* p);
template <> __device__ inline float4 load4f<float>(const float* p) {
    return *reinterpret_cast<const float4*>(p);
}
template <> __device__ inline float4 load4f<__half>(const __half* p) {
    __half2 a = *reinterpret_cast<const __half2*>(p);
    __half2 b = *reinterpret_cast<const __half2*>(p + 2);
    float2 fa = __half22float2(a), fb = __half22float2(b);
    return make_float4(fa.x, fa.y, fb.x, fb.y);
}

template <int K, typename TA>
__global__ __launch_bounds__(256) void k_gemm(const TA* __restrict__ A,
                                              const float* __restrict__ W,
                                              __half* __restrict__ out, int n) {
    __shared__ float wt[K * 65];
    __shared__ float xs[64 * 36];

    const int tid = threadIdx.x;
    const int n0 = blockIdx.x * 64;

    for (int idx = tid; idx < FDIM * K; idx += 256) {
        int fr = idx / K;
        int kr = idx - fr * K;
        wt[kr * 65 + fr] = W[idx];
    }

    const int f = tid & 63;
    const int q = tid >> 6;
    float acc[16];
#pragma unroll
    for (int j = 0; j < 16; ++j) acc[j] = 0.f;

    for (int kc = 0; kc < K; kc += 32) {
        __syncthreads();
#pragma unroll
        for (int u = tid; u < 512; u += 256) {
            int node = u >> 3;
            int k4 = u & 7;
            int gn = n0 + node;
            float4 a = make_float4(0.f, 0.f, 0.f, 0.f);
            if (gn < n) a = load4f(&A[(size_t)gn * K + kc + k4 * 4]);
            *reinterpret_cast<float4*>(&xs[node * 36 + k4 * 4]) = a;
        }
        __syncthreads();

#pragma unroll
        for (int kk = 0; kk < 32; kk += 4) {
            float w0 = wt[(kc + kk + 0) * 65 + f];
            float w1 = wt[(kc + kk + 1) * 65 + f];
            float w2 = wt[(kc + kk + 2) * 65 + f];
            float w3 = wt[(kc + kk + 3) * 65 + f];
#pragma unroll
            for (int jj = 0; jj < 16; ++jj) {
                int j = jj * 4 + q;
                float4 av = *reinterpret_cast<const float4*>(&xs[j * 36 + kk]);
                acc[jj] = fmaf(av.x, w0, fmaf(av.y, w1, fmaf(av.z, w2, fmaf(av.w, w3, acc[jj]))));
            }
        }
    }

#pragma unroll
    for (int jj = 0; jj < 16; ++jj) {
        int node = n0 + jj * 4 + q;
        if (node < n) out[(size_t)node * FDIM + f] = __float2half(acc[jj]);
    }
}

// ============ fused dgconv gather x3 + self-loop + bias + relu ============
// one 64-lane wave per node. CSR row walk is WAVE-UNIFORM: beg/end forced to
// SGPRs -> csr entry loads become s_load (scalar cache), unpack is SALU, no
// shfl, no per-lane CSR loads. Each lane only issues the h-row vector load.

__global__ __launch_bounds__(256) void k_gather(const __half* __restrict__ h,
                                                const float* __restrict__ dis,     // [3][N]
                                                const int* __restrict__ rowptr,    // [3][N+1]
                                                const unsigned* __restrict__ csr,  // [3][E]
                                                const float* __restrict__ bias,    // [64]
                                                __half* __restrict__ cat,          // [N][192]
                                                int N, int E) {
    int i = blockIdx.x * 4 + (threadIdx.x >> 6);
    if (i >= N) return;
    const int lane = threadIdx.x & 63;

    const float hv = __half2float(h[(size_t)i * FDIM + lane]);
    const float b = bias[lane];

#pragma unroll
    for (int g = 0; g < 3; ++g) {
        const int* rp = rowptr + g * (N + 1);
        const unsigned* cg = csr + (size_t)g * E;
        const int beg = __builtin_amdgcn_readfirstlane(rp[i]);
        const int end = __builtin_amdgcn_readfirstlane(rp[i + 1]);
        float dg = dis[g * N + i];

        float acc0 = 0.f, acc1 = 0.f, acc2 = 0.f, acc3 = 0.f;
        int j = beg;
        for (; j + 4 <= end; j += 4) {
            unsigned u0 = cg[j + 0];
            unsigned u1 = cg[j + 1];
            unsigned u2 = cg[j + 2];
            unsigned u3 = cg[j + 3];
            const __half* p0 = h + (size_t)(u0 & 0xFFFFu) * FDIM;
            const __half* p1 = h + (size_t)(u1 & 0xFFFFu) * FDIM;
            const __half* p2 = h + (size_t)(u2 & 0xFFFFu) * FDIM;
            const __half* p3 = h + (size_t)(u3 & 0xFFFFu) * FDIM;
            float a0 = __half2float(p0[lane]);
            float a1 = __half2float(p1[lane]);
            float a2 = __half2float(p2[lane]);
            float a3 = __half2float(p3[lane]);
            float v0 = __half2float(__ushort_as_half((unsigned short)(u0 >> 16)));
            float v1 = __half2float(__ushort_as_half((unsigned short)(u1 >> 16)));
            float v2 = __half2float(__ushort_as_half((unsigned short)(u2 >> 16)));
            float v3 = __half2float(__ushort_as_half((unsigned short)(u3 >> 16)));
            acc0 = fmaf(v0, a0, acc0);
            acc1 = fmaf(v1, a1, acc1);
            acc2 = fmaf(v2, a2, acc2);
            acc3 = fmaf(v3, a3, acc3);
        }
        for (; j < end; ++j) {           // wave-uniform tail (end is SGPR)
            unsigned u0 = cg[j];
            float a0 = __half2float(h[(size_t)(u0 & 0xFFFFu) * FDIM + lane]);
            float v0 = __half2float(__ushort_as_half((unsigned short)(u0 >> 16)));
            acc0 = fmaf(v0, a0, acc0);
        }
        float outv = dg * ((acc0 + acc1) + (acc2 + acc3)) + dg * dg * hv + b;
        cat[(size_t)i * CATDIM + g * FDIM + lane] = __float2half(outv > 0.f ? outv : 0.f);
    }
}

// ============ head: pointwise conv (16 out) + log_softmax (fp16 cat) ============

__global__ __launch_bounds__(256) void k_final(const __half* __restrict__ cat,
                                               const float* __restrict__ convw,  // [16][192]
                                               const float* __restrict__ convb,  // [16]
                                               float* __restrict__ out, int n) {
    __shared__ float wl[16 * 196];
    __shared__ float bl[16];
    const int tid = threadIdx.x;
    for (int t = tid; t < 16 * 192; t += 256) {
        int o = t / 192;
        int k = t - o * 192;
        wl[o * 196 + k] = convw[t];
    }
    if (tid < 16) bl[tid] = convb[tid];
    __syncthreads();

    const int o = tid & 15;
    const int node = blockIdx.x * 16 + (tid >> 4);
    const int nc = node < n ? node : n - 1;

    const float4* xr4 = reinterpret_cast<const float4*>(cat + (size_t)nc * CATDIM);
    const float* wr = &wl[o * 196];
    float acc = bl[o];
#pragma unroll
    for (int k8 = 0; k8 < CATDIM / 8; ++k8) {
        float4 raw = xr4[k8];
        const __half2* hp = reinterpret_cast<const __half2*>(&raw);
        float2 f0 = __half22float2(hp[0]);
        float2 f1 = __half22float2(hp[1]);
        float2 f2 = __half22float2(hp[2]);
        float2 f3 = __half22float2(hp[3]);
        const float* w8 = wr + k8 * 8;
        acc += f0.x * w8[0] + f0.y * w8[1] + f1.x * w8[2] + f1.y * w8[3] +
               f2.x * w8[4] + f2.y * w8[5] + f3.x * w8[6] + f3.y * w8[7];
    }

    float m = acc;
    m = fmaxf(m, __shfl_xor(m, 1));
    m = fmaxf(m, __shfl_xor(m, 2));
    m = fmaxf(m, __shfl_xor(m, 4));
    m = fmaxf(m, __shfl_xor(m, 8));
    float s = __expf(acc - m);
    s += __shfl_xor(s, 1);
    s += __shfl_xor(s, 2);
    s += __shfl_xor(s, 4);
    s += __shfl_xor(s, 8);
    if (node < n) out[(size_t)node * 16 + o] = acc - m - logf(s);
}

// ============ launch ============

extern "C" void kernel_launch(void* const* d_in, const int* in_sizes, int n_in,
                              void* d_out, int out_size, void* d_ws, size_t ws_size,
                              hipStream_t stream) {
    const float* x      = (const float*)d_in[0];
    const int*   ei     = (const int*)d_in[1];
    const int*   e_in   = (const int*)d_in[2];
    const int*   e_out  = (const int*)d_in[3];
    const float* in_w   = (const float*)d_in[4];
    const float* out_w  = (const float*)d_in[5];
    const float* lin1_w = (const float*)d_in[6];
    const float* lin2_w = (const float*)d_in[7];
    const float* bias1  = (const float*)d_in[8];
    const float* bias2  = (const float*)d_in[9];
    const float* conv_w = (const float*)d_in[10];
    const float* conv_b = (const float*)d_in[11];
    float* out = (float*)d_out;

    const int N = in_sizes[0] / 128;
    const int E = in_sizes[1] / 2;
    const int NB = (N + 63) >> 6;              // dest buckets of 64 nodes
    const int nchunks = (E + CH - 1) / CH;
    const int L = NB * nchunks;
    const int nblkS = (L + SCTILE - 1) / SCTILE;   // scan blocks per graph (<=256)

    // workspace layout (4B units; wider types kept 8B/16B aligned)
    float* ws = (float*)d_ws;
    size_t o = 0;
    float* dis    = ws + o;            o += (size_t)3 * N;
    int*   rowptr = (int*)(ws + o);    o += ((size_t)3 * (N + 1) + 1) & ~1ull;
    int*   bbase  = (int*)(ws + o);    o += ((size_t)3 * (NB + 1) + 1) & ~1ull;
    int*   bsum   = (int*)(ws + o);    o += ((size_t)3 * nblkS + 1) & ~1ull;
    int*   bh     = (int*)(ws + o);    o += ((size_t)3 * L + 3) & ~3ull;
    __half* h     = (__half*)(ws + o); o += (size_t)N * (FDIM / 2);       // fp16
    o = (o + 3) & ~3ull;
    unsigned* csr = (unsigned*)(ws + o); o += (size_t)3 * E;              // 4B packed
    o = (o + 3) & ~3ull;
    __half* cat   = (__half*)(ws + o); o += (size_t)N * (CATDIM / 2);     // fp16
    int2*  barr   = (int2*)cat;        // alias: bucket array dead before cat written

    const int B = 256;

    // CSR build: deterministic two-pass binning (no global atomics)
    hipLaunchKernelGGL(k_chist, dim3(nchunks, 3), dim3(B), 0, stream, ei, e_in, e_out, bh, NB, nchunks, E);
    hipLaunchKernelGGL(k_scan_a, dim3(nblkS, 3), dim3(B), 0, stream, bh, bsum, L, nblkS);
    hipLaunchKernelGGL(k_scan_b, dim3(3), dim3(B), 0, stream, bsum, nblkS);
    hipLaunchKernelGGL(k_scan_c, dim3(nblkS, 3), dim3(B), 0, stream, bh, bsum, L, nblkS);
    hipLaunchKernelGGL(k_bbase, dim3((3 * NB + B - 1) / B), dim3(B), 0, stream, bh, bbase, NB, nchunks, E);
    hipLaunchKernelGGL(k_cfill, dim3(nchunks, 3), dim3(B), 0, stream,
                       ei, e_in, e_out, in_w, out_w, bh, barr, NB, nchunks, E);
    hipLaunchKernelGGL(k_bsort, dim3(NB, 3), dim3(B), 0, stream,
                       barr, bbase, csr, rowptr, dis, N, E, NB);
    hipLaunchKernelGGL(k_scale, dim3((3 * E + B - 1) / B), dim3(B), 0, stream, csr, dis, N, E);

    // layer 1
    hipLaunchKernelGGL((k_gemm<128, float>), dim3((N + 63) / 64), dim3(B), 0, stream, x, lin1_w, h, N);
    hipLaunchKernelGGL(k_gather, dim3((N + 3) / 4), dim3(B), 0, stream,
                       h, dis, rowptr, csr, bias1, cat, N, E);

    // layer 2
    hipLaunchKernelGGL((k_gemm<192, __half>), dim3((N + 63) / 64), dim3(B), 0, stream, cat, lin2_w, h, N);
    hipLaunchKernelGGL(k_gather, dim3((N + 3) / 4), dim3(B), 0, stream,
                       h, dis, rowptr, csr, bias2, cat, N, E);

    // head
    hipLaunchKernelGGL(k_final, dim3((N + 15) / 16), dim3(B), 0, stream, cat, conv_w, conv_b, out, N);
}

// Round 9
// 409.038 us; speedup vs baseline: 2.3760x; 1.0300x over previous
//
#include <hip/hip_runtime.h>
#include <hip/hip_fp16.h>
#include <math.h>

#define FDIM 64
#define CATDIM 192
#define CH 8192      // edges per chunk in the binning passes
#define MAXNB 1024   // max dest buckets (N<65536)
#define SCTILE 1024  // elements per block in the bh scan

// ============ pass H: per-chunk LDS histogram over dest buckets ============

__global__ __launch_bounds__(256) void k_chist(const int* __restrict__ ei0,
                                               const int* __restrict__ ei1,
                                               const int* __restrict__ ei2,
                                               int* __restrict__ bh,   // [3][NB][nchunks]
                                               int NB, int nchunks, int E) {
    __shared__ int hist[MAXNB];
    const int c = blockIdx.x, g = blockIdx.y, tid = threadIdx.x;
    const int* dest = (g == 0 ? ei0 : g == 1 ? ei1 : ei2) + E;

    for (int i = tid; i < NB; i += 256) hist[i] = 0;
    __syncthreads();

    const int lo = c * CH, hi = min(E, lo + CH);
    for (int i = lo + tid; i < hi; i += 256) atomicAdd(&hist[dest[i] >> 6], 1);
    __syncthreads();

    for (int i = tid; i < NB; i += 256)
        bh[((size_t)g * NB + i) * nchunks + c] = hist[i];
}

// ============ 3-phase parallel exclusive scan of bh per graph ============

__global__ __launch_bounds__(256) void k_scan_a(const int* __restrict__ bh,
                                                int* __restrict__ bsum,   // [3][nblkS]
                                                int L, int nblkS) {
    __shared__ int s[256];
    const int b = blockIdx.x, g = blockIdx.y, tid = threadIdx.x;
    const int* data = bh + (size_t)g * L;
    const int base = b * SCTILE + tid * 4;
    int v = 0;
#pragma unroll
    for (int j = 0; j < 4; ++j) {
        int idx = base + j;
        if (idx < L) v += data[idx];
    }
    s[tid] = v;
    __syncthreads();
    for (int d = 128; d > 0; d >>= 1) {
        if (tid < d) s[tid] += s[tid + d];
        __syncthreads();
    }
    if (tid == 0) bsum[g * nblkS + b] = s[0];
}

__global__ __launch_bounds__(256) void k_scan_b(int* __restrict__ bsum, int nblkS) {
    __shared__ int s[256];
    const int g = blockIdx.x, tid = threadIdx.x;
    int v = (tid < nblkS) ? bsum[g * nblkS + tid] : 0;
    s[tid] = v;
    __syncthreads();
    for (int d = 1; d < 256; d <<= 1) {
        int t = (tid >= d) ? s[tid - d] : 0;
        __syncthreads();
        s[tid] += t;
        __syncthreads();
    }
    if (tid < nblkS) bsum[g * nblkS + tid] = s[tid] - v;   // exclusive
}

__global__ __launch_bounds__(256) void k_scan_c(int* __restrict__ bh,
                                                const int* __restrict__ bsum,
                                                int L, int nblkS) {
    __shared__ int s[256];
    const int b = blockIdx.x, g = blockIdx.y, tid = threadIdx.x;
    int* data = bh + (size_t)g * L;
    const int base = b * SCTILE + tid * 4;

    int e0 = 0, e1 = 0, e2 = 0, e3 = 0;
    if (base + 0 < L) e0 = data[base + 0];
    if (base + 1 < L) e1 = data[base + 1];
    if (base + 2 < L) e2 = data[base + 2];
    if (base + 3 < L) e3 = data[base + 3];
    int tot = e0 + e1 + e2 + e3;
    s[tid] = tot;
    __syncthreads();
    for (int d = 1; d < 256; d <<= 1) {
        int t = (tid >= d) ? s[tid - d] : 0;
        __syncthreads();
        s[tid] += t;
        __syncthreads();
    }
    int run = bsum[g * nblkS + b] + s[tid] - tot;
    if (base + 0 < L) { data[base + 0] = run; run += e0; }
    if (base + 1 < L) { data[base + 1] = run; run += e1; }
    if (base + 2 < L) { data[base + 2] = run; run += e2; }
    if (base + 3 < L) { data[base + 3] = run; run += e3; }
}

// ============ bucket bases from scanned bh ============

__global__ void k_bbase(const int* __restrict__ bh, int* __restrict__ bbase,
                        int NB, int nchunks, int E) {
    int i = blockIdx.x * blockDim.x + threadIdx.x;
    if (i >= 3 * NB) return;
    int g = i / NB, b = i - g * NB;
    bbase[g * (NB + 1) + b] = bh[((size_t)g * NB + b) * nchunks];
    if (b == 0) bbase[g * (NB + 1) + NB] = E;
}

// ============ pass F: deterministic binned scatter (LDS cursors only) ============

__global__ __launch_bounds__(256) void k_cfill(const int* __restrict__ ei0,
                                               const int* __restrict__ ei1,
                                               const int* __restrict__ ei2,
                                               const float* __restrict__ w1,
                                               const float* __restrict__ w2,
                                               const int* __restrict__ bh,  // scanned bases
                                               int2* __restrict__ barr,     // [3][E]
                                               int NB, int nchunks, int E) {
    __shared__ int cur[MAXNB];
    const int c = blockIdx.x, g = blockIdx.y, tid = threadIdx.x;
    const int* e = (g == 0 ? ei0 : g == 1 ? ei1 : ei2);
    const float* w = (g == 1 ? w1 : w2);
    const int* srcp = e;
    const int* dest = e + E;
    int2* bout = barr + (size_t)g * E;

    for (int i = tid; i < NB; i += 256)
        cur[i] = bh[((size_t)g * NB + i) * nchunks + c];
    __syncthreads();

    const int lo = c * CH, hi = min(E, lo + CH);
    for (int i = lo + tid; i < hi; i += 256) {
        int d = dest[i];
        int slot = atomicAdd(&cur[d >> 6], 1);
        float wv = (g == 0) ? 0.f : w[i];
        bout[slot] = make_int2(srcp[i] | ((d & 63) << 16), __float_as_int(wv));
    }
}

// ============ per-bucket counting sort -> final CSR (4B packed) + rowptr + dis ============
// csr entry: src:16 | fp16(w):16  (w rescaled to dis[src]*w by k_scale)

__global__ __launch_bounds__(256) void k_bsort(const int2* __restrict__ barr,  // [3][E]
                                               const int* __restrict__ bbase,  // [3][NB+1]
                                               unsigned* __restrict__ csr,     // [3][E]
                                               int* __restrict__ rowptr,       // [3][N+1]
                                               float* __restrict__ dis,        // [3][N]
                                               int N, int E, int NB) {
    __shared__ int hist[64];
    __shared__ float wsum[64];
    __shared__ int cur[64];
    __shared__ int sc[64];

    const int b = blockIdx.x, g = blockIdx.y, tid = threadIdx.x;
    const int2* bin = barr + (size_t)g * E;
    const int beg = bbase[g * (NB + 1) + b];
    const int end = bbase[g * (NB + 1) + b + 1];

    if (tid < 64) { hist[tid] = 0; wsum[tid] = 1.0f; }   // 1.0 = self-loop weight
    __syncthreads();

    for (int t = beg + tid; t < end; t += 256) {
        int2 p = bin[t];
        int dl = (p.x >> 16) & 63;
        atomicAdd(&hist[dl], 1);
        if (g) atomicAdd(&wsum[dl], __int_as_float(p.y));
    }
    __syncthreads();

    if (tid < 64) sc[tid] = hist[tid];
    __syncthreads();
    for (int d = 1; d < 64; d <<= 1) {
        int t = 0;
        if (tid < 64 && tid >= d) t = sc[tid - d];
        __syncthreads();
        if (tid < 64) sc[tid] += t;
        __syncthreads();
    }
    if (tid < 64) {
        int excl = sc[tid] - hist[tid];
        cur[tid] = excl;
        int node = b * 64 + tid;
        if (node < N) {
            rowptr[g * (N + 1) + node] = beg + excl;
            float s = g ? wsum[tid] : (1.0f + (float)hist[tid]);
            dis[g * N + node] = rsqrtf(s);
        }
    }
    if (b == NB - 1 && tid == 0) rowptr[g * (N + 1) + N] = end;
    __syncthreads();

    for (int t = beg + tid; t < end; t += 256) {
        int2 p = bin[t];
        int dl = (p.x >> 16) & 63;
        int pos = atomicAdd(&cur[dl], 1);
        unsigned short wb = __half_as_ushort(__float2half(__int_as_float(p.y)));
        csr[(size_t)g * E + beg + pos] = (unsigned)(p.x & 0xFFFF) | ((unsigned)wb << 16);
    }
}

// ============ premultiply val by dis[src] (fp32 math, fp16 store) ============

__global__ void k_scale(unsigned* __restrict__ csr, const float* __restrict__ dis,
                        int N, int E) {
    int idx = blockIdx.x * blockDim.x + threadIdx.x;
    if (idx >= 3 * E) return;
    int g = idx >= 2 * E ? 2 : (idx >= E ? 1 : 0);
    unsigned u = csr[idx];
    int s = u & 0xFFFFu;
    float d = dis[g * N + s];
    float v = (g == 0) ? d
                       : __half2float(__ushort_as_half((unsigned short)(u >> 16))) * d;
    csr[idx] = (u & 0xFFFFu) |
               ((unsigned)__half_as_ushort(__float2half(v)) << 16);
}

// ============ GEMM: out[n][64] = A[n][K] * W[64][K]^T, fp16 output ============

template <typename T> __device__ inline float4 load4f(const T* p);
template <> __device__ inline float4 load4f<float>(const float* p) {
    return *reinterpret_cast<const float4*>(p);
}
template <> __device__ inline float4 load4f<__half>(const __half* p) {
    __half2 a = *reinterpret_cast<const __half2*>(p);
    __half2 b = *reinterpret_cast<const __half2*>(p + 2);
    float2 fa = __half22float2(a), fb = __half22float2(b);
    return make_float4(fa.x, fa.y, fb.x, fb.y);
}

template <int K, typename TA>
__global__ __launch_bounds__(256) void k_gemm(const TA* __restrict__ A,
                                              const float* __restrict__ W,
                                              __half* __restrict__ out, int n) {
    __shared__ float wt[K * 65];
    __shared__ float xs[64 * 36];

    const int tid = threadIdx.x;
    const int n0 = blockIdx.x * 64;

    for (int idx = tid; idx < FDIM * K; idx += 256) {
        int fr = idx / K;
        int kr = idx - fr * K;
        wt[kr * 65 + fr] = W[idx];
    }

    const int f = tid & 63;
    const int q = tid >> 6;
    float acc[16];
#pragma unroll
    for (int j = 0; j < 16; ++j) acc[j] = 0.f;

    for (int kc = 0; kc < K; kc += 32) {
        __syncthreads();
#pragma unroll
        for (int u = tid; u < 512; u += 256) {
            int node = u >> 3;
            int k4 = u & 7;
            int gn = n0 + node;
            float4 a = make_float4(0.f, 0.f, 0.f, 0.f);
            if (gn < n) a = load4f(&A[(size_t)gn * K + kc + k4 * 4]);
            *reinterpret_cast<float4*>(&xs[node * 36 + k4 * 4]) = a;
        }
        __syncthreads();

#pragma unroll
        for (int kk = 0; kk < 32; kk += 4) {
            float w0 = wt[(kc + kk + 0) * 65 + f];
            float w1 = wt[(kc + kk + 1) * 65 + f];
            float w2 = wt[(kc + kk + 2) * 65 + f];
            float w3 = wt[(kc + kk + 3) * 65 + f];
#pragma unroll
            for (int jj = 0; jj < 16; ++jj) {
                int j = jj * 4 + q;
                float4 av = *reinterpret_cast<const float4*>(&xs[j * 36 + kk]);
                acc[jj] = fmaf(av.x, w0, fmaf(av.y, w1, fmaf(av.z, w2, fmaf(av.w, w3, acc[jj]))));
            }
        }
    }

#pragma unroll
    for (int jj = 0; jj < 16; ++jj) {
        int node = n0 + jj * 4 + q;
        if (node < n) out[(size_t)node * FDIM + f] = __float2half(acc[jj]);
    }
}

// ============ fused dgconv gather x3 + self-loop + bias + relu ============
// one 64-lane wave per node. CSR row walk is wave-uniform (SGPR s_loads),
// 8-way unrolled: 8 independent h-row loads in flight per iteration to hide
// the ~400-500cy L2-miss/L3 latency of the random row reads.

__global__ __launch_bounds__(256) void k_gather(const __half* __restrict__ h,
                                                const float* __restrict__ dis,     // [3][N]
                                                const int* __restrict__ rowptr,    // [3][N+1]
                                                const unsigned* __restrict__ csr,  // [3][E]
                                                const float* __restrict__ bias,    // [64]
                                                __half* __restrict__ cat,          // [N][192]
                                                int N, int E) {
    int i = blockIdx.x * 4 + (threadIdx.x >> 6);
    if (i >= N) return;
    const int lane = threadIdx.x & 63;

    const float hv = __half2float(h[(size_t)i * FDIM + lane]);
    const float b = bias[lane];

#pragma unroll
    for (int g = 0; g < 3; ++g) {
        const int* rp = rowptr + g * (N + 1);
        const unsigned* cg = csr + (size_t)g * E;
        const int beg = __builtin_amdgcn_readfirstlane(rp[i]);
        const int end = __builtin_amdgcn_readfirstlane(rp[i + 1]);
        float dg = dis[g * N + i];

        float acc0 = 0.f, acc1 = 0.f, acc2 = 0.f, acc3 = 0.f;
        float acc4 = 0.f, acc5 = 0.f, acc6 = 0.f, acc7 = 0.f;
        int j = beg;
        for (; j + 8 <= end; j += 8) {
            unsigned u0 = cg[j + 0];
            unsigned u1 = cg[j + 1];
            unsigned u2 = cg[j + 2];
            unsigned u3 = cg[j + 3];
            unsigned u4 = cg[j + 4];
            unsigned u5 = cg[j + 5];
            unsigned u6 = cg[j + 6];
            unsigned u7 = cg[j + 7];
            float a0 = __half2float(h[(size_t)(u0 & 0xFFFFu) * FDIM + lane]);
            float a1 = __half2float(h[(size_t)(u1 & 0xFFFFu) * FDIM + lane]);
            float a2 = __half2float(h[(size_t)(u2 & 0xFFFFu) * FDIM + lane]);
            float a3 = __half2float(h[(size_t)(u3 & 0xFFFFu) * FDIM + lane]);
            float a4 = __half2float(h[(size_t)(u4 & 0xFFFFu) * FDIM + lane]);
            float a5 = __half2float(h[(size_t)(u5 & 0xFFFFu) * FDIM + lane]);
            float a6 = __half2float(h[(size_t)(u6 & 0xFFFFu) * FDIM + lane]);
            float a7 = __half2float(h[(size_t)(u7 & 0xFFFFu) * FDIM + lane]);
            acc0 = fmaf(__half2float(__ushort_as_half((unsigned short)(u0 >> 16))), a0, acc0);
            acc1 = fmaf(__half2float(__ushort_as_half((unsigned short)(u1 >> 16))), a1, acc1);
            acc2 = fmaf(__half2float(__ushort_as_half((unsigned short)(u2 >> 16))), a2, acc2);
            acc3 = fmaf(__half2float(__ushort_as_half((unsigned short)(u3 >> 16))), a3, acc3);
            acc4 = fmaf(__half2float(__ushort_as_half((unsigned short)(u4 >> 16))), a4, acc4);
            acc5 = fmaf(__half2float(__ushort_as_half((unsigned short)(u5 >> 16))), a5, acc5);
            acc6 = fmaf(__half2float(__ushort_as_half((unsigned short)(u6 >> 16))), a6, acc6);
            acc7 = fmaf(__half2float(__ushort_as_half((unsigned short)(u7 >> 16))), a7, acc7);
        }
        if (j + 4 <= end) {
            unsigned u0 = cg[j + 0];
            unsigned u1 = cg[j + 1];
            unsigned u2 = cg[j + 2];
            unsigned u3 = cg[j + 3];
            float a0 = __half2float(h[(size_t)(u0 & 0xFFFFu) * FDIM + lane]);
            float a1 = __half2float(h[(size_t)(u1 & 0xFFFFu) * FDIM + lane]);
            float a2 = __half2float(h[(size_t)(u2 & 0xFFFFu) * FDIM + lane]);
            float a3 = __half2float(h[(size_t)(u3 & 0xFFFFu) * FDIM + lane]);
            acc0 = fmaf(__half2float(__ushort_as_half((unsigned short)(u0 >> 16))), a0, acc0);
            acc1 = fmaf(__half2float(__ushort_as_half((unsigned short)(u1 >> 16))), a1, acc1);
            acc2 = fmaf(__half2float(__ushort_as_half((unsigned short)(u2 >> 16))), a2, acc2);
            acc3 = fmaf(__half2float(__ushort_as_half((unsigned short)(u3 >> 16))), a3, acc3);
            j += 4;
        }
        for (; j < end; ++j) {           // wave-uniform tail (end is SGPR)
            unsigned u0 = cg[j];
            float a0 = __half2float(h[(size_t)(u0 & 0xFFFFu) * FDIM + lane]);
            acc0 = fmaf(__half2float(__ushort_as_half((unsigned short)(u0 >> 16))), a0, acc0);
        }
        float outv = dg * (((acc0 + acc1) + (acc2 + acc3)) + ((acc4 + acc5) + (acc6 + acc7)))
                   + dg * dg * hv + b;
        cat[(size_t)i * CATDIM + g * FDIM + lane] = __float2half(outv > 0.f ? outv : 0.f);
    }
}

// ============ head: pointwise conv (16 out) + log_softmax (fp16 cat) ============

__global__ __launch_bounds__(256) void k_final(const __half* __restrict__ cat,
                                               const float* __restrict__ convw,  // [16][192]
                                               const float* __restrict__ convb,  // [16]
                                               float* __restrict__ out, int n) {
    __shared__ float wl[16 * 196];
    __shared__ float bl[16];
    const int tid = threadIdx.x;
    for (int t = tid; t < 16 * 192; t += 256) {
        int o = t / 192;
        int k = t - o * 192;
        wl[o * 196 + k] = convw[t];
    }
    if (tid < 16) bl[tid] = convb[tid];
    __syncthreads();

    const int o = tid & 15;
    const int node = blockIdx.x * 16 + (tid >> 4);
    const int nc = node < n ? node : n - 1;

    const float4* xr4 = reinterpret_cast<const float4*>(cat + (size_t)nc * CATDIM);
    const float* wr = &wl[o * 196];
    float acc = bl[o];
#pragma unroll
    for (int k8 = 0; k8 < CATDIM / 8; ++k8) {
        float4 raw = xr4[k8];
        const __half2* hp = reinterpret_cast<const __half2*>(&raw);
        float2 f0 = __half22float2(hp[0]);
        float2 f1 = __half22float2(hp[1]);
        float2 f2 = __half22float2(hp[2]);
        float2 f3 = __half22float2(hp[3]);
        const float* w8 = wr + k8 * 8;
        acc += f0.x * w8[0] + f0.y * w8[1] + f1.x * w8[2] + f1.y * w8[3] +
               f2.x * w8[4] + f2.y * w8[5] + f3.x * w8[6] + f3.y * w8[7];
    }

    float m = acc;
    m = fmaxf(m, __shfl_xor(m, 1));
    m = fmaxf(m, __shfl_xor(m, 2));
    m = fmaxf(m, __shfl_xor(m, 4));
    m = fmaxf(m, __shfl_xor(m, 8));
    float s = __expf(acc - m);
    s += __shfl_xor(s, 1);
    s += __shfl_xor(s, 2);
    s += __shfl_xor(s, 4);
    s += __shfl_xor(s, 8);
    if (node < n) out[(size_t)node * 16 + o] = acc - m - logf(s);
}

// ============ launch ============

extern "C" void kernel_launch(void* const* d_in, const int* in_sizes, int n_in,
                              void* d_out, int out_size, void* d_ws, size_t ws_size,
                              hipStream_t stream) {
    const float* x      = (const float*)d_in[0];
    const int*   ei     = (const int*)d_in[1];
    const int*   e_in   = (const int*)d_in[2];
    const int*   e_out  = (const int*)d_in[3];
    const float* in_w   = (const float*)d_in[4];
    const float* out_w  = (const float*)d_in[5];
    const float* lin1_w = (const float*)d_in[6];
    const float* lin2_w = (const float*)d_in[7];
    const float* bias1  = (const float*)d_in[8];
    const float* bias2  = (const float*)d_in[9];
    const float* conv_w = (const float*)d_in[10];
    const float* conv_b = (const float*)d_in[11];
    float* out = (float*)d_out;

    const int N = in_sizes[0] / 128;
    const int E = in_sizes[1] / 2;
    const int NB = (N + 63) >> 6;              // dest buckets of 64 nodes
    const int nchunks = (E + CH - 1) / CH;
    const int L = NB * nchunks;
    const int nblkS = (L + SCTILE - 1) / SCTILE;   // scan blocks per graph (<=256)

    // workspace layout (4B units; wider types kept 8B/16B aligned)
    float* ws = (float*)d_ws;
    size_t o = 0;
    float* dis    = ws + o;            o += (size_t)3 * N;
    int*   rowptr = (int*)(ws + o);    o += ((size_t)3 * (N + 1) + 1) & ~1ull;
    int*   bbase  = (int*)(ws + o);    o += ((size_t)3 * (NB + 1) + 1) & ~1ull;
    int*   bsum   = (int*)(ws + o);    o += ((size_t)3 * nblkS + 1) & ~1ull;
    int*   bh     = (int*)(ws + o);    o += ((size_t)3 * L + 3) & ~3ull;
    __half* h     = (__half*)(ws + o); o += (size_t)N * (FDIM / 2);       // fp16
    o = (o + 3) & ~3ull;
    unsigned* csr = (unsigned*)(ws + o); o += (size_t)3 * E;              // 4B packed
    o = (o + 3) & ~3ull;
    __half* cat   = (__half*)(ws + o); o += (size_t)N * (CATDIM / 2);     // fp16
    int2*  barr   = (int2*)cat;        // alias: bucket array dead before cat written

    const int B = 256;

    // CSR build: deterministic two-pass binning (no global atomics)
    hipLaunchKernelGGL(k_chist, dim3(nchunks, 3), dim3(B), 0, stream, ei, e_in, e_out, bh, NB, nchunks, E);
    hipLaunchKernelGGL(k_scan_a, dim3(nblkS, 3), dim3(B), 0, stream, bh, bsum, L, nblkS);
    hipLaunchKernelGGL(k_scan_b, dim3(3), dim3(B), 0, stream, bsum, nblkS);
    hipLaunchKernelGGL(k_scan_c, dim3(nblkS, 3), dim3(B), 0, stream, bh, bsum, L, nblkS);
    hipLaunchKernelGGL(k_bbase, dim3((3 * NB + B - 1) / B), dim3(B), 0, stream, bh, bbase, NB, nchunks, E);
    hipLaunchKernelGGL(k_cfill, dim3(nchunks, 3), dim3(B), 0, stream,
                       ei, e_in, e_out, in_w, out_w, bh, barr, NB, nchunks, E);
    hipLaunchKernelGGL(k_bsort, dim3(NB, 3), dim3(B), 0, stream,
                       barr, bbase, csr, rowptr, dis, N, E, NB);
    hipLaunchKernelGGL(k_scale, dim3((3 * E + B - 1) / B), dim3(B), 0, stream, csr, dis, N, E);

    // layer 1
    hipLaunchKernelGGL((k_gemm<128, float>), dim3((N + 63) / 64), dim3(B), 0, stream, x, lin1_w, h, N);
    hipLaunchKernelGGL(k_gather, dim3((N + 3) / 4), dim3(B), 0, stream,
                       h, dis, rowptr, csr, bias1, cat, N, E);

    // layer 2
    hipLaunchKernelGGL((k_gemm<192, __half>), dim3((N + 63) / 64), dim3(B), 0, stream, cat, lin2_w, h, N);
    hipLaunchKernelGGL(k_gather, dim3((N + 3) / 4), dim3(B), 0, stream,
                       h, dis, rowptr, csr, bias2, cat, N, E);

    // head
    hipLaunchKernelGGL(k_final, dim3((N + 15) / 16), dim3(B), 0, stream, cat, conv_w, conv_b, out, N);
}